// Round 12
// baseline (1221.300 us; speedup 1.0000x reference)
//
#include <hip/hip_runtime.h>

typedef _Float16 f16;
typedef _Float16 f16x8 __attribute__((ext_vector_type(8)));
typedef _Float16 f16x4 __attribute__((ext_vector_type(4)));
typedef float f32x4 __attribute__((ext_vector_type(4)));
typedef int i32x4 __attribute__((ext_vector_type(4)));

static constexpr int BB = 2, T = 1024, D = 1024, FFD = 4096, V = 32000, NL = 6;
static constexpr int M = BB * T;                       // 2048 rows
static constexpr int ROWS_PER_LAYER = 4*D + 2*FFD + D; // 13312 scale rows per layer
static constexpr size_t QL = 4ull*D*D + 2ull*FFD*D + (size_t)D*FFD; // 16.78M elems/layer
static constexpr int NT = 64, CT = T / NT;             // scan: 64 chunks x 16 steps
static constexpr int RKV = 3*D;                        // fused rkv row stride
static constexpr int NKB = FFD / 128;                  // 32 K-chunks for oc dequant

// direct global->LDS, 16B per lane. lds base wave-uniform; HW writes lane i at
// lds + i*16 (m104).
__device__ __forceinline__ void gload16b(const void* g, void* l) {
  __builtin_amdgcn_global_load_lds(
      (const __attribute__((address_space(1))) void*)g,
      (__attribute__((address_space(3))) void*)l, 16, 0, 0);
}
// counted vmcnt wait: allow the newest stage's N loads to remain in flight.
template<int N> __device__ __forceinline__ void vm_wait() {
  static_assert(N >= 2 && N <= 4, "unsupported vmcnt");
  if constexpr (N == 2) asm volatile("s_waitcnt vmcnt(2)" ::: "memory");
  else if constexpr (N == 3) asm volatile("s_waitcnt vmcnt(3)" ::: "memory");
  else                       asm volatile("s_waitcnt vmcnt(4)" ::: "memory");
}
// ring-phase boundary: all waves' reads of the oldest buffer are complete;
// sched_barrier pins the next stage AFTER the barrier.
__device__ __forceinline__ void ring_barrier() {
  __builtin_amdgcn_s_barrier();
  __builtin_amdgcn_sched_barrier(0);
}

// ---------------------------------------------------------------------------
// Single-pass per-row scale + ternary-quantize to i8 (EXACT: w_q in {-1,0,1}).
// qw layout per layer: [qr(D,D) qk qv qo | q1(FFD,D) q2 | qoc(D,FFD)]
// ---------------------------------------------------------------------------
__global__ __launch_bounds__(256) void quant_kernel(
    const float* __restrict__ Wr, const float* __restrict__ Wk,
    const float* __restrict__ Wv, const float* __restrict__ Wo,
    const float* __restrict__ W1, const float* __restrict__ W2,
    const float* __restrict__ Woc, char* __restrict__ qw, float* __restrict__ scales)
{
  const int r = blockIdx.x, l = blockIdx.y;
  const float* base; int len; size_t dst;
  if (r < 4*D) {
    const int m = r >> 10, row = r & (D-1);
    const float* Wm = (m==0) ? Wr : (m==1) ? Wk : (m==2) ? Wv : Wo;
    base = Wm + (size_t)l*D*D + (size_t)row*D; len = D;
    dst = (size_t)l*QL + (size_t)m*D*D + (size_t)row*D;
  } else if (r < 4*D + 2*FFD) {
    int row = r - 4*D;
    const int m = row >= FFD; if (m) row -= FFD;
    const float* Wm = m ? W2 : W1;
    base = Wm + (size_t)l*FFD*D + (size_t)row*D; len = D;
    dst = (size_t)l*QL + 4ull*D*D + (size_t)m*FFD*D + (size_t)row*D;
  } else {
    const int row = r - (4*D + 2*FFD);
    base = Woc + (size_t)l*D*FFD + (size_t)row*FFD; len = FFD;
    dst = (size_t)l*QL + 4ull*D*D + 2ull*FFD*D + (size_t)row*FFD;
  }
  const int nv = len >> 10;        // float4s per thread: 1 (len=1024) or 4 (4096)
  float4 rv[4];
  float sum = 0.f;
  #pragma unroll 4
  for (int i = 0; i < 4; ++i) {
    if (i < nv) {
      rv[i] = reinterpret_cast<const float4*>(base)[threadIdx.x + i*256];
      sum += fabsf(rv[i].x) + fabsf(rv[i].y) + fabsf(rv[i].z) + fabsf(rv[i].w);
    }
  }
  #pragma unroll
  for (int off = 32; off > 0; off >>= 1) sum += __shfl_down(sum, off);
  __shared__ float red[4]; __shared__ float sbc;
  if ((threadIdx.x & 63) == 0) red[threadIdx.x >> 6] = sum;
  __syncthreads();
  if (threadIdx.x == 0) {
    const float s = fmaxf((red[0]+red[1]+red[2]+red[3]) / (float)len, 1e-5f);
    sbc = s;
    scales[(size_t)l*ROWS_PER_LAYER + r] = s;
  }
  __syncthreads();
  const float hs = 0.5f * sbc;
  #pragma unroll 4
  for (int i = 0; i < 4; ++i) {
    if (i < nv) {
      const float4 v = rv[i];
      char4 q;
      q.x = v.x > hs ? 1 : (v.x < -hs ? -1 : 0);
      q.y = v.y > hs ? 1 : (v.y < -hs ? -1 : 0);
      q.z = v.z > hs ? 1 : (v.z < -hs ? -1 : 0);
      q.w = v.w > hs ? 1 : (v.w < -hs ? -1 : 0);
      reinterpret_cast<char4*>(qw + dst)[threadIdx.x + i*256] = q;
    }
  }
}

// ---------------------------------------------------------------------------
// Per-vocab-row i8 quantize of embed: s = max|row|/127; q = rint(w/s).
// ---------------------------------------------------------------------------
__global__ __launch_bounds__(256) void quant_embed_kernel(
    const float* __restrict__ embed, char* __restrict__ q, float* __restrict__ sw)
{
  const int row = blockIdx.x;
  const float4 v = reinterpret_cast<const float4*>(embed + (size_t)row*D)[threadIdx.x];
  float mx = fmaxf(fmaxf(fabsf(v.x), fabsf(v.y)), fmaxf(fabsf(v.z), fabsf(v.w)));
  #pragma unroll
  for (int off = 32; off > 0; off >>= 1) mx = fmaxf(mx, __shfl_down(mx, off));
  __shared__ float red[4]; __shared__ float sbc;
  if ((threadIdx.x & 63) == 0) red[threadIdx.x >> 6] = mx;
  __syncthreads();
  if (threadIdx.x == 0) {
    const float m = fmaxf(fmaxf(red[0], red[1]), fmaxf(red[2], red[3]));
    const float s = fmaxf(m, 1e-8f) * (1.f/127.f);
    sbc = 1.f / s;
    sw[row] = s;
  }
  __syncthreads();
  const float inv = sbc;
  char4 o;
  o.x = (char)__float2int_rn(v.x * inv); o.y = (char)__float2int_rn(v.y * inv);
  o.z = (char)__float2int_rn(v.z * inv); o.w = (char)__float2int_rn(v.w * inv);
  reinterpret_cast<char4*>(q + (size_t)row*D)[threadIdx.x] = o;
}

// ---------------------------------------------------------------------------
// h = rmsnorm(embed[idx], ln_in_w), f32 out. One block (256 thr) per row.
// ---------------------------------------------------------------------------
__global__ __launch_bounds__(256) void embed_rms_kernel(
    const int* __restrict__ idx, const float* __restrict__ embed,
    const float* __restrict__ g, float* __restrict__ h)
{
  const int row = blockIdx.x;
  const int tok = idx[row];
  const float4 xv = reinterpret_cast<const float4*>(embed + (size_t)tok*D)[threadIdx.x];
  float ss = xv.x*xv.x + xv.y*xv.y + xv.z*xv.z + xv.w*xv.w;
  #pragma unroll
  for (int off = 32; off > 0; off >>= 1) ss += __shfl_down(ss, off);
  __shared__ float red[4];
  if ((threadIdx.x & 63) == 0) red[threadIdx.x >> 6] = ss;
  __syncthreads();
  const float mean = (red[0]+red[1]+red[2]+red[3]) * (1.f/(float)D);
  const float rn = rsqrtf(mean + 1e-6f);
  const float4 gv = reinterpret_cast<const float4*>(g)[threadIdx.x];
  float4 ov;
  ov.x = xv.x*rn*gv.x; ov.y = xv.y*rn*gv.y; ov.z = xv.z*rn*gv.z; ov.w = xv.w*rn*gv.w;
  reinterpret_cast<float4*>(h + (size_t)row*D)[threadIdx.x] = ov;
}

// ---------------------------------------------------------------------------
// xn8 = i8-quantized rmsnorm(x, g) with per-row scale sx (fused, one pass).
// ---------------------------------------------------------------------------
__global__ __launch_bounds__(256) void rms_i8_kernel(
    const float* __restrict__ x, const float* __restrict__ g,
    char* __restrict__ q, float* __restrict__ sx)
{
  const int row = blockIdx.x;
  const float4 xv = reinterpret_cast<const float4*>(x + (size_t)row*D)[threadIdx.x];
  const float4 gv = reinterpret_cast<const float4*>(g)[threadIdx.x];
  float4 pv;
  pv.x = xv.x*gv.x; pv.y = xv.y*gv.y; pv.z = xv.z*gv.z; pv.w = xv.w*gv.w;
  float ss = xv.x*xv.x + xv.y*xv.y + xv.z*xv.z + xv.w*xv.w;
  float mg = fmaxf(fmaxf(fabsf(pv.x), fabsf(pv.y)), fmaxf(fabsf(pv.z), fabsf(pv.w)));
  #pragma unroll
  for (int off = 32; off > 0; off >>= 1) {
    ss += __shfl_down(ss, off);
    mg = fmaxf(mg, __shfl_down(mg, off));
  }
  __shared__ float reds[4], redm[4]; __shared__ float sbc;
  if ((threadIdx.x & 63) == 0) { reds[threadIdx.x >> 6] = ss; redm[threadIdx.x >> 6] = mg; }
  __syncthreads();
  if (threadIdx.x == 0) {
    const float mean = (reds[0]+reds[1]+reds[2]+reds[3]) * (1.f/(float)D);
    const float rn = rsqrtf(mean + 1e-6f);
    const float vmax = rn * fmaxf(fmaxf(redm[0], redm[1]), fmaxf(redm[2], redm[3]));
    const float s = fmaxf(vmax, 1e-8f) * (1.f/127.f);
    sx[row] = s;
    sbc = rn / s;
  }
  __syncthreads();
  const float f = sbc;
  char4 o;
  o.x = (char)__float2int_rn(pv.x * f); o.y = (char)__float2int_rn(pv.y * f);
  o.z = (char)__float2int_rn(pv.z * f); o.w = (char)__float2int_rn(pv.w * f);
  reinterpret_cast<char4*>(q + (size_t)row*D)[threadIdx.x] = o;
}

// ---------------------------------------------------------------------------
// Fused: h += p0 + p1; xn8 = i8 rmsnorm(h, g) + per-row scale sx.
// ---------------------------------------------------------------------------
__global__ __launch_bounds__(256) void rms_radd_i8_kernel(
    float* __restrict__ h, const float* __restrict__ p0,
    const float* __restrict__ p1, const float* __restrict__ g,
    char* __restrict__ q, float* __restrict__ sx)
{
  const int row = blockIdx.x;
  const size_t off = (size_t)row*D/4 + threadIdx.x;
  float4 hv = reinterpret_cast<const float4*>(h)[off];
  const float4 a = reinterpret_cast<const float4*>(p0)[off];
  const float4 b = reinterpret_cast<const float4*>(p1)[off];
  hv.x += a.x + b.x; hv.y += a.y + b.y; hv.z += a.z + b.z; hv.w += a.w + b.w;
  reinterpret_cast<float4*>(h)[off] = hv;
  const float4 gv = reinterpret_cast<const float4*>(g)[threadIdx.x];
  float4 pv;
  pv.x = hv.x*gv.x; pv.y = hv.y*gv.y; pv.z = hv.z*gv.z; pv.w = hv.w*gv.w;
  float ss = hv.x*hv.x + hv.y*hv.y + hv.z*hv.z + hv.w*hv.w;
  float mg = fmaxf(fmaxf(fabsf(pv.x), fabsf(pv.y)), fmaxf(fabsf(pv.z), fabsf(pv.w)));
  #pragma unroll
  for (int o2 = 32; o2 > 0; o2 >>= 1) {
    ss += __shfl_down(ss, o2);
    mg = fmaxf(mg, __shfl_down(mg, o2));
  }
  __shared__ float reds[4], redm[4]; __shared__ float sbc;
  if ((threadIdx.x & 63) == 0) { reds[threadIdx.x >> 6] = ss; redm[threadIdx.x >> 6] = mg; }
  __syncthreads();
  if (threadIdx.x == 0) {
    const float mean = (reds[0]+reds[1]+reds[2]+reds[3]) * (1.f/(float)D);
    const float rn = rsqrtf(mean + 1e-6f);
    const float vmax = rn * fmaxf(fmaxf(redm[0], redm[1]), fmaxf(redm[2], redm[3]));
    const float s = fmaxf(vmax, 1e-8f) * (1.f/127.f);
    sx[row] = s;
    sbc = rn / s;
  }
  __syncthreads();
  const float f = sbc;
  char4 o;
  o.x = (char)__float2int_rn(pv.x * f); o.y = (char)__float2int_rn(pv.y * f);
  o.z = (char)__float2int_rn(pv.z * f); o.w = (char)__float2int_rn(pv.w * f);
  reinterpret_cast<char4*>(q + (size_t)row*D)[threadIdx.x] = o;
}

// ---------------------------------------------------------------------------
// Time-mix recurrence: chunked prefix sum over T.
// ---------------------------------------------------------------------------
__global__ __launch_bounds__(256) void scan1_kernel(
    const float* __restrict__ k, const float* __restrict__ v, int ld,
    const float* __restrict__ decay, float* __restrict__ part)
{
  const int d = blockIdx.x*256 + threadIdx.x;
  const int c = blockIdx.y, b = blockIdx.z;
  const float dec = 1.f / (1.f + expf(-decay[d]));
  const float ldc = logf(fmaxf(dec, 1e-7f));
  float sum = 0.f;
  const int row0 = b*T + c*CT;
  #pragma unroll 4
  for (int t = 0; t < CT; ++t) {
    const size_t i = (size_t)(row0 + t)*ld + d;
    const float scale = expf((float)(c*CT + t) * ldc);
    sum += (k[i] * v[i]) / fmaxf(scale, 1e-10f);
  }
  part[((size_t)b*NT + c)*D + d] = sum;
}

__global__ __launch_bounds__(256) void scan23_kernel(
    const float* __restrict__ r, const float* __restrict__ k,
    const float* __restrict__ v, int ld, const float* __restrict__ decay,
    const float* __restrict__ part, float* __restrict__ rs)
{
  const int d = blockIdx.x*256 + threadIdx.x;
  const int c = blockIdx.y, b = blockIdx.z;
  const float dec = 1.f / (1.f + expf(-decay[d]));
  const float ldc = logf(fmaxf(dec, 1e-7f));
  float cum = 0.f;
  for (int j = 0; j < c; ++j) cum += part[((size_t)b*NT + j)*D + d];
  const int row0 = b*T + c*CT;
  #pragma unroll 4
  for (int t = 0; t < CT; ++t) {
    const size_t i = (size_t)(row0 + t)*ld + d;
    const float scale = expf((float)(c*CT + t) * ldc);
    cum += (k[i] * v[i]) / fmaxf(scale, 1e-10f);
    rs[(size_t)(row0 + t)*D + d] = r[i] * (cum * scale);
  }
}

// fallback-path kernels -------------------------------------------------------
__global__ __launch_bounds__(256) void rms_f16_kernel(
    const float* __restrict__ x, const float* __restrict__ g, f16* __restrict__ o)
{
  const int row = blockIdx.x;
  const float4 xv = reinterpret_cast<const float4*>(x + (size_t)row*D)[threadIdx.x];
  float ss = xv.x*xv.x + xv.y*xv.y + xv.z*xv.z + xv.w*xv.w;
  #pragma unroll
  for (int off = 32; off > 0; off >>= 1) ss += __shfl_down(ss, off);
  __shared__ float red[4];
  if ((threadIdx.x & 63) == 0) red[threadIdx.x >> 6] = ss;
  __syncthreads();
  const float mean = (red[0]+red[1]+red[2]+red[3]) * (1.f/(float)D);
  const float rn = rsqrtf(mean + 1e-6f);
  const float4 gv = reinterpret_cast<const float4*>(g)[threadIdx.x];
  f16x4 ov;
  ov[0] = (f16)(xv.x*rn*gv.x); ov[1] = (f16)(xv.y*rn*gv.y);
  ov[2] = (f16)(xv.z*rn*gv.z); ov[3] = (f16)(xv.w*rn*gv.w);
  reinterpret_cast<f16x4*>(o + (size_t)row*D)[threadIdx.x] = ov;
}

__global__ __launch_bounds__(256) void scan2_kernel(float* __restrict__ part)
{
  const int d = blockIdx.x*256 + threadIdx.x;
  const int b = blockIdx.y;
  float run = 0.f;
  #pragma unroll 8
  for (int c = 0; c < NT; ++c) {
    const size_t i = ((size_t)b*NT + c)*D + d;
    const float t = part[i];
    part[i] = run;
    run += t;
  }
}

__global__ __launch_bounds__(256) void scan3_kernel(
    const float* __restrict__ r, const float* __restrict__ k,
    const float* __restrict__ v, int ld, const float* __restrict__ decay,
    const float* __restrict__ part, float* __restrict__ rs)
{
  const int d = blockIdx.x*256 + threadIdx.x;
  const int c = blockIdx.y, b = blockIdx.z;
  const float dec = 1.f / (1.f + expf(-decay[d]));
  const float ldc = logf(fmaxf(dec, 1e-7f));
  float cum = part[((size_t)b*NT + c)*D + d];
  const int row0 = b*T + c*CT;
  #pragma unroll 4
  for (int t = 0; t < CT; ++t) {
    const size_t i = (size_t)(row0 + t)*ld + d;
    const float scale = expf((float)(c*CT + t) * ldc);
    cum += (k[i] * v[i]) / fmaxf(scale, 1e-10f);
    rs[(size_t)(row0 + t)*D + d] = r[i] * (cum * scale);
  }
}

__global__ __launch_bounds__(256) void silumul_kernel(
    const f16* __restrict__ a, const f16* __restrict__ b, f16* __restrict__ o, int n4)
{
  const int i = blockIdx.x*256 + threadIdx.x;
  if (i >= n4) return;
  const f16x4 av = reinterpret_cast<const f16x4*>(a)[i];
  const f16x4 bv = reinterpret_cast<const f16x4*>(b)[i];
  f16x4 ov;
  #pragma unroll
  for (int j = 0; j < 4; ++j) {
    const float x = (float)av[j];
    ov[j] = (f16)((x / (1.f + expf(-x))) * (float)bv[j]);
  }
  reinterpret_cast<f16x4*>(o)[i] = ov;
}

// ---------------------------------------------------------------------------
// XCD-chunked bijective block swizzle (m204).
// ---------------------------------------------------------------------------
__device__ __forceinline__ int xcd_swizzle(int fid, int nwg) {
  const int q = nwg >> 3, r = nwg & 7, x = fid & 7, o = fid >> 3;
  return (x < r ? x*(q+1) : r*(q+1) + (x-r)*q) + o;
}

// ---------------------------------------------------------------------------
// RING GEMM, INT8 (r11-proven): 3-buffer, depth-2 prefetch, counted vmcnt,
// ONE barrier/K-step. K-step 64, mfma_i32_16x16x64_i8.
// out[M,N] = epi( sx[row] * scl[col] * (A8 @ W8^T) ), f32 out. BN=128.
// EPI: 0 none, 2 +resid, 3 sigmoid iff col<D.
// ---------------------------------------------------------------------------
template<int BM, int NW, int EPI>
__global__ __launch_bounds__(NW*64) void gemm_i8_kernel(
    const char* __restrict__ A, const char* __restrict__ Bq,
    const float* __restrict__ sx, const float* __restrict__ scl,
    const float* __restrict__ resid, float* __restrict__ outp, int N, int K)
{
  constexpr int WN = 2;
  constexpr int WM = NW / WN;
  constexpr int MF = BM / (WM*16);
  constexpr int ACALLS = BM / (16*NW);
  constexpr int BCALLS = 128 / (16*NW);
  constexpr int VCNT = ACALLS + BCALLS;
  __shared__ __align__(16) char As[3][BM*64];
  __shared__ __align__(16) char Bs[3][128*64];

  const int tid = threadIdx.x;
  const int wave = tid >> 6, lane = tid & 63;
  const int gx = gridDim.x, nwg = gx * gridDim.y;
  const int wg = xcd_swizzle(blockIdx.x + blockIdx.y*gx, nwg);
  const int m0 = (wg % gx) * BM, n0 = (wg / gx) * 128;
  const int lr = lane & 15, kg = lane >> 4;
  const int wm0 = (wave / WN) * (MF*16), wn0 = (wave % WN) * 64;
  const int grow = lane >> 2;
  const int gcol = (lane & 3) * 16;
  const char* Ab = A  + (size_t)(m0 + grow)*K + gcol;
  const char* Bb = Bq + (size_t)(n0 + grow)*K + gcol;

  const int NKT = K / 64;

  auto stage = [&](int buf, int k0) {
    #pragma unroll
    for (int c = 0; c < ACALLS; ++c) {
      const int rb = (c*NW + wave) * 16;
      gload16b(Ab + (size_t)rb*K + k0, &As[buf][rb*64]);
    }
    #pragma unroll
    for (int c = 0; c < BCALLS; ++c) {
      const int rb = (c*NW + wave) * 16;
      gload16b(Bb + (size_t)rb*K + k0, &Bs[buf][rb*64]);
    }
  };

  i32x4 acc[MF][4] = {};
  stage(0, 0);
  stage(1, 64);

  int cur = 0;
  for (int t = 0; t < NKT; ++t) {
    vm_wait<VCNT>();
    ring_barrier();
    if (t + 2 < NKT) {
      int nb = cur + 2; if (nb >= 3) nb -= 3;
      stage(nb, (t + 2) * 64);
    }
    i32x4 af[MF], bf[4];
    #pragma unroll
    for (int i = 0; i < MF; ++i)
      af[i] = *reinterpret_cast<const i32x4*>(&As[cur][(wm0 + i*16 + lr)*64 + kg*16]);
    #pragma unroll
    for (int j = 0; j < 4; ++j)
      bf[j] = *reinterpret_cast<const i32x4*>(&Bs[cur][(wn0 + j*16 + lr)*64 + kg*16]);
    #pragma unroll
    for (int i = 0; i < MF; ++i)
      #pragma unroll
      for (int j = 0; j < 4; ++j)
        acc[i][j] = __builtin_amdgcn_mfma_i32_16x16x64_i8(af[i], bf[j], acc[i][j], 0, 0, 0);
    ++cur; if (cur == 3) cur = 0;
  }

  // C/D frag layout: col=lane&15, row=(lane>>4)*4+e (dtype-independent)
  #pragma unroll
  for (int j = 0; j < 4; ++j) {
    const int col = n0 + wn0 + j*16 + lr;
    const float sv = scl[col];
    #pragma unroll
    for (int i = 0; i < MF; ++i) {
      #pragma unroll
      for (int e = 0; e < 4; ++e) {
        const int row = m0 + wm0 + i*16 + kg*4 + e;
        float y = (float)acc[i][j][e] * sx[row] * sv;
        if (EPI == 3 && col < D) y = 1.f / (1.f + expf(-y));
        if (EPI == 2) y += resid[(size_t)row*N + col];
        outp[(size_t)row*N + col] = y;
      }
    }
  }
}

// ---------------------------------------------------------------------------
// OC GEMM, INT8 with per-row-per-K-chunk A scales (from fused FFN quant):
// split-K x2; i32 chunk accumulation (exact, chunk=128) dequantized into f32
// accumulators every 2 ring steps: facc += (float)iacc * sax[row*NKB + kb].
// BM=64, NW=4, BN=128. Writes f32 partials at outp + z*M*N.
// ---------------------------------------------------------------------------
__global__ __launch_bounds__(256) void gemm_oc_i8_kernel(
    const char* __restrict__ A, const char* __restrict__ Bq,
    const float* __restrict__ sax, const float* __restrict__ scl,
    float* __restrict__ outp, int N, int K)
{
  constexpr int BM = 64, NW = 4, WN = 2;
  constexpr int MF = 2;                  // BM/( (NW/WN)*16 )
  constexpr int ACALLS = 1, BCALLS = 2, VCNT = 3;
  __shared__ __align__(16) char As[3][BM*64];
  __shared__ __align__(16) char Bs[3][128*64];

  const int tid = threadIdx.x;
  const int wave = tid >> 6, lane = tid & 63;
  const int gx = gridDim.x, nwg = gx * gridDim.y;
  const int wg = xcd_swizzle(blockIdx.x + blockIdx.y*gx, nwg);
  const int m0 = (wg % gx) * BM, n0 = (wg / gx) * 128;
  const int lr = lane & 15, kg = lane >> 4;
  const int wm0 = (wave / WN) * (MF*16), wn0 = (wave % WN) * 64;
  const int grow = lane >> 2;
  const int gcol = (lane & 3) * 16;
  const char* Ab = A  + (size_t)(m0 + grow)*K + gcol;
  const char* Bb = Bq + (size_t)(n0 + grow)*K + gcol;

  const int kc = K / gridDim.z;
  const int kbeg = blockIdx.z * kc;
  const size_t obase = (size_t)blockIdx.z * M * (size_t)N;
  const int NKT = kc / 64;

  auto stage = [&](int buf, int k0) {
    #pragma unroll
    for (int c = 0; c < ACALLS; ++c) {
      const int rb = (c*NW + wave) * 16;
      gload16b(Ab + (size_t)rb*K + k0, &As[buf][rb*64]);
    }
    #pragma unroll
    for (int c = 0; c < BCALLS; ++c) {
      const int rb = (c*NW + wave) * 16;
      gload16b(Bb + (size_t)rb*K + k0, &Bs[buf][rb*64]);
    }
  };

  i32x4 iacc[MF][4] = {};
  f32x4 facc[MF][4] = {};
  stage(0, kbeg);
  stage(1, kbeg + 64);

  int cur = 0;
  for (int t = 0; t < NKT; ++t) {
    vm_wait<VCNT>();
    ring_barrier();
    if (t + 2 < NKT) {
      int nb = cur + 2; if (nb >= 3) nb -= 3;
      stage(nb, kbeg + (t + 2) * 64);
    }
    i32x4 af[MF], bf[4];
    #pragma unroll
    for (int i = 0; i < MF; ++i)
      af[i] = *reinterpret_cast<const i32x4*>(&As[cur][(wm0 + i*16 + lr)*64 + kg*16]);
    #pragma unroll
    for (int j = 0; j < 4; ++j)
      bf[j] = *reinterpret_cast<const i32x4*>(&Bs[cur][(wn0 + j*16 + lr)*64 + kg*16]);
    #pragma unroll
    for (int i = 0; i < MF; ++i)
      #pragma unroll
      for (int j = 0; j < 4; ++j)
        iacc[i][j] = __builtin_amdgcn_mfma_i32_16x16x64_i8(af[i], bf[j], iacc[i][j], 0, 0, 0);
    if (t & 1) {  // 128-K chunk complete -> dequant into f32 accumulator
      const int kb = (kbeg >> 7) + (t >> 1);
      #pragma unroll
      for (int i = 0; i < MF; ++i) {
        #pragma unroll
        for (int e = 0; e < 4; ++e) {
          const int row = m0 + wm0 + i*16 + kg*4 + e;
          const float s = sax[(size_t)row*NKB + kb];
          #pragma unroll
          for (int j = 0; j < 4; ++j) {
            facc[i][j][e] += (float)iacc[i][j][e] * s;
            iacc[i][j][e] = 0;
          }
        }
      }
    }
    ++cur; if (cur == 3) cur = 0;
  }

  #pragma unroll
  for (int j = 0; j < 4; ++j) {
    const int col = n0 + wn0 + j*16 + lr;
    const float sv = scl[col];
    #pragma unroll
    for (int i = 0; i < MF; ++i) {
      #pragma unroll
      for (int e = 0; e < 4; ++e) {
        const int row = m0 + wm0 + i*16 + kg*4 + e;
        outp[obase + (size_t)row*N + col] = facc[i][j][e] * sv;
      }
    }
  }
}

// ---------------------------------------------------------------------------
// RING HEAD GEMM, INT8 + LDS-coalesced f32 epilogue.
// 128x256 tile, 8 waves, K-step 64, ring-3. Epilogue: 4 passes (one per
// wn-strip); writer waves dump a 128x64 f32 tile to reused ring LDS, all
// threads copy out as f32x4 (256B runs).
// ---------------------------------------------------------------------------
__global__ __launch_bounds__(512) void gemm_head_i8_kernel(
    const char* __restrict__ A, const char* __restrict__ Bq,
    const float* __restrict__ sx, const float* __restrict__ sw,
    float* __restrict__ out, int N, int K)
{
  constexpr int BM = 128, BN = 256;
  __shared__ __align__(16) char smem[3*BM*64 + 3*BN*64];   // 73728 B
  char* AsB = smem;                    // [3][BM*64]
  char* BsB = smem + 3*BM*64;          // [3][BN*64]
  const int tid = threadIdx.x;
  const int wave = tid >> 6, lane = tid & 63;
  const int gx = gridDim.x, nwg = gx * gridDim.y;
  const int wg = xcd_swizzle(blockIdx.x + blockIdx.y*gx, nwg);
  const int m0 = (wg % gx) * BM, n0 = (wg / gx) * BN;
  const int lr = lane & 15, kg = lane >> 4;
  const int wm0 = (wave >> 2) * 64, wn0 = (wave & 3) * 64;
  const int grow = lane >> 2;
  const int gcol = (lane & 3) * 16;
  const char* Ab = A  + (size_t)(m0 + grow)*K + gcol;
  const char* Bb = Bq + (size_t)(n0 + grow)*K + gcol;

  auto stage = [&](int buf, int k0) {
    gload16b(Ab + (size_t)(wave*16)*K + k0, AsB + buf*BM*64 + (wave*16)*64);
    gload16b(Bb + (size_t)(wave*16)*K + k0, BsB + buf*BN*64 + (wave*16)*64);
    gload16b(Bb + (size_t)((wave+8)*16)*K + k0, BsB + buf*BN*64 + ((wave+8)*16)*64);
  };

  i32x4 acc[4][4] = {};
  stage(0, 0);
  stage(1, 64);

  const int NKT = K / 64;
  int cur = 0;
  for (int t = 0; t < NKT; ++t) {
    vm_wait<3>();
    ring_barrier();
    if (t + 2 < NKT) {
      int nb = cur + 2; if (nb >= 3) nb -= 3;
      stage(nb, (t + 2) * 64);
    }
    i32x4 af[4], bf[4];
    #pragma unroll
    for (int i = 0; i < 4; ++i)
      af[i] = *reinterpret_cast<const i32x4*>(AsB + cur*BM*64 + (wm0 + i*16 + lr)*64 + kg*16);
    #pragma unroll
    for (int j = 0; j < 4; ++j)
      bf[j] = *reinterpret_cast<const i32x4*>(BsB + cur*BN*64 + (wn0 + j*16 + lr)*64 + kg*16);
    #pragma unroll
    for (int i = 0; i < 4; ++i)
      #pragma unroll
      for (int j = 0; j < 4; ++j)
        acc[i][j] = __builtin_amdgcn_mfma_i32_16x16x64_i8(af[i], bf[j], acc[i][j], 0, 0, 0);
    ++cur; if (cur == 3) cur = 0;
  }

  // Epilogue: per wn-strip, writers fill a [128][64] f32 LDS tile, everyone
  // copies it out coalesced (f32x4; 4 consecutive x4 per thread = 64B runs,
  // 4-lane groups cover 256B rows).
  float* otile = reinterpret_cast<float*>(smem);           // 32KB
  #pragma unroll
  for (int pass = 0; pass < 4; ++pass) {
    __syncthreads();
    if ((wave & 3) == pass) {
      #pragma unroll
      for (int j = 0; j < 4; ++j) {
        const int col = n0 + wn0 + j*16 + lr;
        const float scw = sw[col];
        #pragma unroll
        for (int i = 0; i < 4; ++i) {
          #pragma unroll
          for (int e = 0; e < 4; ++e) {
            const int rb = wm0 + i*16 + kg*4 + e;
            otile[rb*64 + j*16 + lr] = (float)acc[i][j][e] * sx[m0 + rb] * scw;
          }
        }
      }
    }
    __syncthreads();
    const int slot0 = tid * 4;                 // 2048 f32x4 slots
    #pragma unroll
    for (int s = 0; s < 4; ++s) {
      const int slot = slot0 + s;
      const int r = slot >> 4, c4 = slot & 15;
      *reinterpret_cast<f32x4*>(&out[(size_t)(m0 + r)*N + n0 + pass*64 + c4*4]) =
          *reinterpret_cast<const f32x4*>(&otile[r*64 + c4*4]);
    }
  }
}

// ---------------------------------------------------------------------------
// RING FUSED FFN GEMM, INT8, fused output quantization:
// g = silu(sx s1 accA) * (sx s2 accB); per-row max over this block's 128
// cols -> s = max/127; writes g8 = rint(g/s) and sax[row*NKB + n0/128] = s.
// 128x128 tile, 8 waves, ring-3, K-step 64.
// ---------------------------------------------------------------------------
__global__ __launch_bounds__(512) void gemm_ffn_i8_kernel(
    const char* __restrict__ A, const char* __restrict__ B1, const char* __restrict__ B2,
    const float* __restrict__ sx, const float* __restrict__ s1, const float* __restrict__ s2,
    char* __restrict__ outg8, float* __restrict__ sax, int N, int K)
{
  constexpr int BM = 128, BN = 128;
  __shared__ __align__(16) char As [3][BM*64];
  __shared__ __align__(16) char B1s[3][BN*64];
  __shared__ __align__(16) char B2s[3][BN*64];
  __shared__ float rmx[2][BM];
  const int tid = threadIdx.x;
  const int wave = tid >> 6, lane = tid & 63;
  const int gx = gridDim.x, nwg = gx * gridDim.y;
  const int wg = xcd_swizzle(blockIdx.x + blockIdx.y*gx, nwg);
  const int m0 = (wg % gx) * BM, n0 = (wg / gx) * BN;
  const int lr = lane & 15, kg = lane >> 4;
  const int wm0 = (wave >> 1) * 32, wn0 = (wave & 1) * 64;  // 8 waves: 4M x 2N
  const int grow = lane >> 2;
  const int gcol = (lane & 3) * 16;
  const char* Ab  = A  + (size_t)(m0 + grow)*K + gcol;
  const char* B1b = B1 + (size_t)(n0 + grow)*K + gcol;
  const char* B2b = B2 + (size_t)(n0 + grow)*K + gcol;

  auto stage = [&](int buf, int k0) {
    const int rb = wave * 16;
    gload16b(Ab  + (size_t)rb*K + k0, &As [buf][rb*64]);
    gload16b(B1b + (size_t)rb*K + k0, &B1s[buf][rb*64]);
    gload16b(B2b + (size_t)rb*K + k0, &B2s[buf][rb*64]);
  };

  i32x4 aca[2][4] = {};
  i32x4 acb[2][4] = {};
  stage(0, 0);
  stage(1, 64);

  const int NKT = K / 64;
  int cur = 0;
  for (int t = 0; t < NKT; ++t) {
    vm_wait<3>();
    ring_barrier();
    if (t + 2 < NKT) {
      int nb = cur + 2; if (nb >= 3) nb -= 3;
      stage(nb, (t + 2) * 64);
    }
    i32x4 af[2], b1f[4], b2f[4];
    #pragma unroll
    for (int i = 0; i < 2; ++i)
      af[i] = *reinterpret_cast<const i32x4*>(&As[cur][(wm0 + i*16 + lr)*64 + kg*16]);
    #pragma unroll
    for (int j = 0; j < 4; ++j) {
      b1f[j] = *reinterpret_cast<const i32x4*>(&B1s[cur][(wn0 + j*16 + lr)*64 + kg*16]);
      b2f[j] = *reinterpret_cast<const i32x4*>(&B2s[cur][(wn0 + j*16 + lr)*64 + kg*16]);
    }
    #pragma unroll
    for (int i = 0; i < 2; ++i)
      #pragma unroll
      for (int j = 0; j < 4; ++j) {
        aca[i][j] = __builtin_amdgcn_mfma_i32_16x16x64_i8(af[i], b1f[j], aca[i][j], 0, 0, 0);
        acb[i][j] = __builtin_amdgcn_mfma_i32_16x16x64_i8(af[i], b2f[j], acb[i][j], 0, 0, 0);
      }
    ++cur; if (cur == 3) cur = 0;
  }

  // compute g, per-row block max, quantize
  float gv[2][4][4];
  float vmax[2][4];   // [i][e], max |g| over this thread's 4 j-cols
  #pragma unroll
  for (int i = 0; i < 2; ++i)
    #pragma unroll
    for (int e = 0; e < 4; ++e) {
      const int row = m0 + wm0 + i*16 + kg*4 + e;
      const float srow = sx[row];
      float mx = 0.f;
      #pragma unroll
      for (int j = 0; j < 4; ++j) {
        const int col = n0 + wn0 + j*16 + lr;
        const float a = (float)aca[i][j][e] * srow * s1[col];
        const float b = (float)acb[i][j][e] * srow * s2[col];
        const float gval = (a / (1.f + expf(-a))) * b;
        gv[i][j][e] = gval;
        mx = fmaxf(mx, fabsf(gval));
      }
      vmax[i][e] = mx;
    }
  // reduce max over the 16-lane lr group (lanes kg*16 .. kg*16+15)
  #pragma unroll
  for (int i = 0; i < 2; ++i)
    #pragma unroll
    for (int e = 0; e < 4; ++e) {
      float mx = vmax[i][e];
      #pragma unroll
      for (int off = 1; off < 16; off <<= 1) mx = fmaxf(mx, __shfl_xor(mx, off));
      vmax[i][e] = mx;
    }
  __syncthreads();   // ring reads done; safe to write rmx
  if (lr == 0) {
    #pragma unroll
    for (int i = 0; i < 2; ++i)
      #pragma unroll
      for (int e = 0; e < 4; ++e)
        rmx[wave & 1][wm0 + i*16 + kg*4 + e] = vmax[i][e];
  }
  __syncthreads();
  const int nblk = n0 >> 7;
  #pragma unroll
  for (int i = 0; i < 2; ++i)
    #pragma unroll
    for (int e = 0; e < 4; ++e) {
      const int rb = wm0 + i*16 + kg*4 + e;
      const float rm = fmaxf(rmx[0][rb], rmx[1][rb]);
      const float s = fmaxf(rm, 1e-8f) * (1.f/127.f);
      const float inv = 1.f / s;
      if ((wave & 1) == 0 && lr == 0)
        sax[(size_t)(m0 + rb)*NKB + nblk] = s;
      #pragma unroll
      for (int j = 0; j < 4; ++j) {
        const int col = n0 + wn0 + j*16 + lr;
        outg8[(size_t)(m0 + rb)*N + col] = (char)__float2int_rn(gv[i][j][e] * inv);
      }
    }
}

// ---------------------------------------------------------------------------
// FALLBACK GEMM: inline quantize from f32 weights (used if ws too small).
// ---------------------------------------------------------------------------
__global__ __launch_bounds__(64) void scales_kernel(
    const float* __restrict__ Wr, const float* __restrict__ Wk,
    const float* __restrict__ Wv, const float* __restrict__ Wo,
    const float* __restrict__ W1, const float* __restrict__ W2,
    const float* __restrict__ Woc, float* __restrict__ s)
{
  const int r = blockIdx.x, l = blockIdx.y;
  const float* base; int len;
  if (r < 4*D) {
    const int m = r >> 10, row = r & (D-1);
    const float* Wm = (m==0) ? Wr : (m==1) ? Wk : (m==2) ? Wv : Wo;
    base = Wm + (size_t)l*D*D + (size_t)row*D; len = D;
  } else if (r < 4*D + 2*FFD) {
    int row = r - 4*D;
    const float* Wm = (row < FFD) ? W1 : W2;
    if (row >= FFD) row -= FFD;
    base = Wm + (size_t)l*FFD*D + (size_t)row*D; len = D;
  } else {
    const int row = r - (4*D + 2*FFD);
    base = Woc + (size_t)l*D*FFD + (size_t)row*FFD; len = FFD;
  }
  float sum = 0.f;
  for (int i = threadIdx.x; i < len; i += 64) sum += fabsf(base[i]);
  #pragma unroll
  for (int off = 32; off > 0; off >>= 1) sum += __shfl_down(sum, off);
  if (threadIdx.x == 0)
    s[(size_t)l*ROWS_PER_LAYER + r] = fmaxf(sum / (float)len, 1e-5f);
}

template<int BM, int EPI, bool QUANT, bool OUTF16>
__global__ __launch_bounds__(256) void gemm_bt_kernel(
    const f16* __restrict__ A, const float* __restrict__ Bw,
    const float* __restrict__ scl, const float* __restrict__ resid,
    void* __restrict__ outp, int N, int K)
{
  constexpr int BN = 128, LDT = 40;
  constexpr int MF = (BM == 128) ? 4 : 2;
  __shared__ f16 As[BM*LDT];
  __shared__ f16 Bs[BN*LDT];
  const int tid = threadIdx.x;
  const int m0 = blockIdx.y * BM, n0 = blockIdx.x * BN;
  const int wave = tid >> 6, lane = tid & 63;
  const int lr = lane & 15, kg = lane >> 4;
  const int wm0 = (wave >> 1) * (MF*16), wn0 = (wave & 1) * 64;
  f32x4 acc[MF][4] = {};
  for (int k0 = 0; k0 < K; k0 += 32) {
    #pragma unroll
    for (int c = 0; c < (BM*4)/256; ++c) {
      const int chunk = tid + c*256;
      const int row = chunk >> 2, c8 = (chunk & 3) << 3;
      *reinterpret_cast<f16x8*>(&As[row*LDT + c8]) =
        *reinterpret_cast<const f16x8*>(A + (size_t)(m0+row)*K + k0 + c8);
    }
    #pragma unroll
    for (int c = 0; c < 2; ++c) {
      const int chunk = tid + c*256;
      const int row = chunk >> 2, c8 = (chunk & 3) << 3;
      const float* bp = Bw + (size_t)(n0+row)*K + k0 + c8;
      const float4 f0 = *reinterpret_cast<const float4*>(bp);
      const float4 f1 = *reinterpret_cast<const float4*>(bp + 4);
      const float wv[8] = {f0.x,f0.y,f0.z,f0.w,f1.x,f1.y,f1.z,f1.w};
      f16x8 qv;
      if (QUANT) {
        const float hs = 0.5f * scl[n0+row];
        #pragma unroll
        for (int j = 0; j < 8; ++j)
          qv[j] = wv[j] > hs ? (f16)1.f : (wv[j] < -hs ? (f16)(-1.f) : (f16)0.f);
      } else {
        #pragma unroll
        for (int j = 0; j < 8; ++j) qv[j] = (f16)wv[j];
      }
      *reinterpret_cast<f16x8*>(&Bs[row*LDT + c8]) = qv;
    }
    __syncthreads();
    f16x8 af[MF], bf[4];
    #pragma unroll
    for (int i = 0; i < MF; ++i)
      af[i] = *reinterpret_cast<const f16x8*>(&As[(wm0 + i*16 + lr)*LDT + kg*8]);
    #pragma unroll
    for (int j = 0; j < 4; ++j)
      bf[j] = *reinterpret_cast<const f16x8*>(&Bs[(wn0 + j*16 + lr)*LDT + kg*8]);
    #pragma unroll
    for (int i = 0; i < MF; ++i)
      #pragma unroll
      for (int j = 0; j < 4; ++j)
        acc[i][j] = __builtin_amdgcn_mfma_f32_16x16x32_f16(af[i], bf[j], acc[i][j], 0, 0, 0);
    __syncthreads();
  }
  #pragma unroll
  for (int j = 0; j < 4; ++j) {
    const int col = n0 + wn0 + j*16 + lr;
    const float sv = QUANT ? scl[col] : 1.f;
    #pragma unroll
    for (int i = 0; i < MF; ++i) {
      #pragma unroll
      for (int e = 0; e < 4; ++e) {
        const int row = m0 + wm0 + i*16 + kg*4 + e;
        float y = acc[i][j][e] * sv;
        if (EPI == 1) y = 1.f / (1.f + expf(-y));
        if (EPI == 2) y += resid[(size_t)row*N + col];
        if (OUTF16) reinterpret_cast<f16*>(outp)[(size_t)row*N + col] = (f16)y;
        else        reinterpret_cast<float*>(outp)[(size_t)row*N + col] = y;
      }
    }
  }
}

// ---------------------------------------------------------------------------
extern "C" void kernel_launch(void* const* d_in, const int* in_sizes, int n_in,
                              void* d_out, int out_size, void* d_ws, size_t ws_size,
                              hipStream_t stream)
{
  (void)in_sizes; (void)n_in; (void)out_size;
  const int*   idx      = (const int*)  d_in[0];
  const float* embed    = (const float*)d_in[1];
  const float* ln_in_w  = (const float*)d_in[2];
  const float* ln1_w    = (const float*)d_in[3];
  const float* Wr       = (const float*)d_in[4];
  const float* Wk       = (const float*)d_in[5];
  const float* Wv       = (const float*)d_in[6];
  const float* Wo_t     = (const float*)d_in[7];
  const float* decay    = (const float*)d_in[8];
  const float* lnx_w    = (const float*)d_in[9];
  const float* ln2_w    = (const float*)d_in[10];
  const float* W1       = (const float*)d_in[11];
  const float* W2       = (const float*)d_in[12];
  const float* Wo_c     = (const float*)d_in[13];
  const float* ln_out_w = (const float*)d_in[14];
  float* out = (float*)d_out;

  char* p = (char*)d_ws;
  auto alloc = [&](size_t bytes) { void* q = (void*)p; p += (bytes + 255) & ~(size_t)255; return q; };
  float* h      = (float*)alloc((size_t)M*D*sizeof(float));
  f16*   xn     = (f16*)  alloc((size_t)M*D*sizeof(f16));       // fallback only
  float* rkv    = (float*)alloc((size_t)M*RKV*sizeof(float));   // r|k|v; reused as split-K partials
  float* rsb    = (float*)alloc((size_t)M*D*sizeof(float));
  f16*   abf    = (f16*)  alloc((size_t)M*FFD*sizeof(f16));     // fallback only
  f16*   bbf    = (f16*)  alloc((size_t)M*FFD*sizeof(f16));     // fallback only
  float* scales = (float*)alloc((size_t)NL*ROWS_PER_LAYER*sizeof(float));
  float* part   = (float*)alloc((size_t)BB*NT*D*sizeof(float));
  const size_t base_need = (size_t)(p - (char*)d_ws);
  const size_t fast_need = base_need + (NL*QL + 256)
      + ((size_t)V*D + 256) + (V*sizeof(float) + 256)
      + ((size_t)M*D + 256) + (M*sizeof(float) + 256)
      + ((size_t)M*FFD + 256) + ((size_t)M*NKB*sizeof(float) + 256);

  embed_rms_kernel<<<M, 256, 0, stream>>>(idx, embed, ln_in_w, h);

  const dim3 gS(D/256, NT, BB);   // scan1/scan23: 512 blocks
  const dim3 gS2(D/256, BB);      // scan2 (fallback): 8 blocks

  if (ws_size >= fast_need) {
    // ================= FAST PATH: i8 weights + i8 activations =================
    char*  qw8  = (char*) alloc(NL*QL);
    char*  emb8 = (char*) alloc((size_t)V*D);
    float* sw   = (float*)alloc((size_t)V*sizeof(float));
    char*  xn8  = (char*) alloc((size_t)M*D);
    float* sx   = (float*)alloc((size_t)M*sizeof(float));
    char*  abf8 = (char*) alloc((size_t)M*FFD);
    float* sax  = (float*)alloc((size_t)M*NKB*sizeof(float));
    quant_kernel<<<dim3(ROWS_PER_LAYER, NL), 256, 0, stream>>>(Wr, Wk, Wv, Wo_t, W1, W2, Wo_c, qw8, scales);
    quant_embed_kernel<<<V, 256, 0, stream>>>(embed, emb8, sw);

    const dim3 gRKV(M/128, RKV/128);     // 16 x 24 = 384 blocks, 8 waves
    const dim3 gO(M/64, D/128);          // 32 x 8  = 256 blocks, 4 waves
    const dim3 gOC(M/64, D/128, 2);      // 512 blocks (split-K x2)
    const dim3 gFFN(M/128, FFD/128);     // 16 x 32 = 512 blocks, 8 waves
    const dim3 gHEAD(M/128, V/256);      // 16 x 125 = 2000 blocks, 8 waves

    rms_i8_kernel<<<M, 256, 0, stream>>>(h, ln1_w, xn8, sx);   // first layer's ln1
    for (int l = 0; l < NL; ++l) {
      const float* sl = scales + (size_t)l*ROWS_PER_LAYER;
      const char* qb = qw8 + (size_t)l*QL;
      const char *qrkv = qb, *qo = qb + 3ull*D*D;
      const char *q1 = qb + 4ull*D*D, *q2 = qb + 4ull*D*D + (size_t)FFD*D;
      const char *qoc = qb + 4ull*D*D + 2ull*(size_t)FFD*D;
      const float* dcy = decay + (size_t)l*D;
      // ---- time mix ----
      gemm_i8_kernel<128,8,3><<<gRKV, 512, 0, stream>>>(xn8, qrkv, sx, sl, nullptr, rkv, RKV, D);
      scan1_kernel<<<gS, 256, 0, stream>>>(rkv + D, rkv + 2*D, RKV, dcy, part);
      scan23_kernel<<<gS, 256, 0, stream>>>(rkv, rkv + D, rkv + 2*D, RKV, dcy, part, rsb);
      rms_i8_kernel<<<M, 256, 0, stream>>>(rsb, lnx_w + (size_t)l*D, xn8, sx);
      gemm_i8_kernel<64,4,2><<<gO, 256, 0, stream>>>(xn8, qo, sx, sl + 3*D, h, h, D, D);
      // ---- channel mix ----
      rms_i8_kernel<<<M, 256, 0, stream>>>(h, ln2_w + (size_t)l*D, xn8, sx);
      gemm_ffn_i8_kernel<<<gFFN, 512, 0, stream>>>(xn8, q1, q2, sx, sl + 4*D, sl + 4*D + FFD, abf8, sax, FFD, D);
      gemm_oc_i8_kernel<<<gOC, 256, 0, stream>>>(abf8, qoc, sax, sl + 4*D + 2*FFD, rkv, D, FFD);
      const float* gnext = (l + 1 < NL) ? (ln1_w + (size_t)(l+1)*D) : ln_out_w;
      rms_radd_i8_kernel<<<M, 256, 0, stream>>>(h, rkv, rkv + (size_t)M*D, gnext, xn8, sx);
    }
    // ---- weight-tied head (A already i8 from last rms_radd) ----
    gemm_head_i8_kernel<<<gHEAD, 512, 0, stream>>>(xn8, emb8, sx, sw, out, V, D);
  } else {
    // ================= FALLBACK: inline-quant f16 path =================
    float* rbuf = rkv;
    float* kbuf = rkv + (size_t)M*D;
    float* vbuf = rkv + 2ull*M*D;
    scales_kernel<<<dim3(ROWS_PER_LAYER, NL), 64, 0, stream>>>(Wr, Wk, Wv, Wo_t, W1, W2, Wo_c, scales);
    const dim3 gD(D/128, M/64);
    const dim3 gF(FFD/128, M/128);
    for (int l = 0; l < NL; ++l) {
      const float* sl = scales + (size_t)l*ROWS_PER_LAYER;
      const float* dcy = decay + (size_t)l*D;
      rms_f16_kernel<<<M, 256, 0, stream>>>(h, ln1_w + (size_t)l*D, xn);
      gemm_bt_kernel<64,1,true,false><<<gD, 256, 0, stream>>>(xn, Wr + (size_t)l*D*D, sl,       nullptr, rbuf, D, D);
      gemm_bt_kernel<64,0,true,false><<<gD, 256, 0, stream>>>(xn, Wk + (size_t)l*D*D, sl + D,   nullptr, kbuf, D, D);
      gemm_bt_kernel<64,0,true,false><<<gD, 256, 0, stream>>>(xn, Wv + (size_t)l*D*D, sl + 2*D, nullptr, vbuf, D, D);
      scan1_kernel<<<gS, 256, 0, stream>>>(kbuf, vbuf, D, dcy, part);
      scan2_kernel<<<gS2, 256, 0, stream>>>(part);
      scan3_kernel<<<gS, 256, 0, stream>>>(rbuf, kbuf, vbuf, D, dcy, part, rsb);
      rms_f16_kernel<<<M, 256, 0, stream>>>(rsb, lnx_w + (size_t)l*D, xn);
      gemm_bt_kernel<64,2,true,false><<<gD, 256, 0, stream>>>(xn, Wo_t + (size_t)l*D*D, sl + 3*D, h, h, D, D);
      rms_f16_kernel<<<M, 256, 0, stream>>>(h, ln2_w + (size_t)l*D, xn);
      gemm_bt_kernel<128,0,true,true><<<gF, 256, 0, stream>>>(xn, W1 + (size_t)l*FFD*D, sl + 4*D,       nullptr, abf, FFD, D);
      gemm_bt_kernel<128,0,true,true><<<gF, 256, 0, stream>>>(xn, W2 + (size_t)l*FFD*D, sl + 4*D + FFD, nullptr, bbf, FFD, D);
      silumul_kernel<<<(M*FFD/4)/256, 256, 0, stream>>>(abf, bbf, abf, M*FFD/4);
      gemm_bt_kernel<64,2,true,false><<<gD, 256, 0, stream>>>(abf, Wo_c + (size_t)l*D*FFD, sl + 4*D + 2*FFD, h, h, D, FFD);
    }
    rms_f16_kernel<<<M, 256, 0, stream>>>(h, ln_out_w, xn);
    gemm_bt_kernel<128,0,false,false><<<dim3(V/128, M/128), 256, 0, stream>>>(xn, embed, nullptr, nullptr, out, V, D);
  }
}

// Round 13
// 1191.265 us; speedup vs baseline: 1.0252x; 1.0252x over previous
//
#include <hip/hip_runtime.h>

typedef _Float16 f16;
typedef _Float16 f16x8 __attribute__((ext_vector_type(8)));
typedef _Float16 f16x4 __attribute__((ext_vector_type(4)));
typedef float f32x4 __attribute__((ext_vector_type(4)));
typedef int i32x4 __attribute__((ext_vector_type(4)));

static constexpr int BB = 2, T = 1024, D = 1024, FFD = 4096, V = 32000, NL = 6;
static constexpr int M = BB * T;                       // 2048 rows
static constexpr int ROWS_PER_LAYER = 4*D + 2*FFD + D; // 13312 scale rows per layer
static constexpr size_t QL = 4ull*D*D + 2ull*FFD*D + (size_t)D*FFD; // 16.78M elems/layer
static constexpr int NT = 64, CT = T / NT;             // scan: 64 chunks x 16 steps
static constexpr int RKV = 3*D;                        // fused rkv row stride

// direct global->LDS, 16B per lane. lds base wave-uniform; HW writes lane i at
// lds + i*16 (m104).
__device__ __forceinline__ void gload16b(const void* g, void* l) {
  __builtin_amdgcn_global_load_lds(
      (const __attribute__((address_space(1))) void*)g,
      (__attribute__((address_space(3))) void*)l, 16, 0, 0);
}
// counted vmcnt wait: allow the newest stage's N loads to remain in flight.
template<int N> __device__ __forceinline__ void vm_wait() {
  static_assert(N >= 2 && N <= 4, "unsupported vmcnt");
  if constexpr (N == 2) asm volatile("s_waitcnt vmcnt(2)" ::: "memory");
  else if constexpr (N == 3) asm volatile("s_waitcnt vmcnt(3)" ::: "memory");
  else                       asm volatile("s_waitcnt vmcnt(4)" ::: "memory");
}
// ring-phase boundary: all waves' reads of the oldest buffer are complete;
// sched_barrier pins the next stage AFTER the barrier.
__device__ __forceinline__ void ring_barrier() {
  __builtin_amdgcn_s_barrier();
  __builtin_amdgcn_sched_barrier(0);
}

// ---------------------------------------------------------------------------
// Single-pass per-row scale + ternary-quantize to i8 (EXACT: w_q in {-1,0,1}).
// qw layout per layer: [qr(D,D) qk qv qo | q1(FFD,D) q2 | qoc(D,FFD)]
// ---------------------------------------------------------------------------
__global__ __launch_bounds__(256) void quant_kernel(
    const float* __restrict__ Wr, const float* __restrict__ Wk,
    const float* __restrict__ Wv, const float* __restrict__ Wo,
    const float* __restrict__ W1, const float* __restrict__ W2,
    const float* __restrict__ Woc, char* __restrict__ qw, float* __restrict__ scales)
{
  const int r = blockIdx.x, l = blockIdx.y;
  const float* base; int len; size_t dst;
  if (r < 4*D) {
    const int m = r >> 10, row = r & (D-1);
    const float* Wm = (m==0) ? Wr : (m==1) ? Wk : (m==2) ? Wv : Wo;
    base = Wm + (size_t)l*D*D + (size_t)row*D; len = D;
    dst = (size_t)l*QL + (size_t)m*D*D + (size_t)row*D;
  } else if (r < 4*D + 2*FFD) {
    int row = r - 4*D;
    const int m = row >= FFD; if (m) row -= FFD;
    const float* Wm = m ? W2 : W1;
    base = Wm + (size_t)l*FFD*D + (size_t)row*D; len = D;
    dst = (size_t)l*QL + 4ull*D*D + (size_t)m*FFD*D + (size_t)row*D;
  } else {
    const int row = r - (4*D + 2*FFD);
    base = Woc + (size_t)l*D*FFD + (size_t)row*FFD; len = FFD;
    dst = (size_t)l*QL + 4ull*D*D + 2ull*FFD*D + (size_t)row*FFD;
  }
  const int nv = len >> 10;
  float4 rv[4];
  float sum = 0.f;
  #pragma unroll 4
  for (int i = 0; i < 4; ++i) {
    if (i < nv) {
      rv[i] = reinterpret_cast<const float4*>(base)[threadIdx.x + i*256];
      sum += fabsf(rv[i].x) + fabsf(rv[i].y) + fabsf(rv[i].z) + fabsf(rv[i].w);
    }
  }
  #pragma unroll
  for (int off = 32; off > 0; off >>= 1) sum += __shfl_down(sum, off);
  __shared__ float red[4]; __shared__ float sbc;
  if ((threadIdx.x & 63) == 0) red[threadIdx.x >> 6] = sum;
  __syncthreads();
  if (threadIdx.x == 0) {
    const float s = fmaxf((red[0]+red[1]+red[2]+red[3]) / (float)len, 1e-5f);
    sbc = s;
    scales[(size_t)l*ROWS_PER_LAYER + r] = s;
  }
  __syncthreads();
  const float hs = 0.5f * sbc;
  #pragma unroll 4
  for (int i = 0; i < 4; ++i) {
    if (i < nv) {
      const float4 v = rv[i];
      char4 q;
      q.x = v.x > hs ? 1 : (v.x < -hs ? -1 : 0);
      q.y = v.y > hs ? 1 : (v.y < -hs ? -1 : 0);
      q.z = v.z > hs ? 1 : (v.z < -hs ? -1 : 0);
      q.w = v.w > hs ? 1 : (v.w < -hs ? -1 : 0);
      reinterpret_cast<char4*>(qw + dst)[threadIdx.x + i*256] = q;
    }
  }
}

// ---------------------------------------------------------------------------
// Per-vocab-row i8 quantize of embed: s = max|row|/127; q = rint(w/s).
// ---------------------------------------------------------------------------
__global__ __launch_bounds__(256) void quant_embed_kernel(
    const float* __restrict__ embed, char* __restrict__ q, float* __restrict__ sw)
{
  const int row = blockIdx.x;
  const float4 v = reinterpret_cast<const float4*>(embed + (size_t)row*D)[threadIdx.x];
  float mx = fmaxf(fmaxf(fabsf(v.x), fabsf(v.y)), fmaxf(fabsf(v.z), fabsf(v.w)));
  #pragma unroll
  for (int off = 32; off > 0; off >>= 1) mx = fmaxf(mx, __shfl_down(mx, off));
  __shared__ float red[4]; __shared__ float sbc;
  if ((threadIdx.x & 63) == 0) red[threadIdx.x >> 6] = mx;
  __syncthreads();
  if (threadIdx.x == 0) {
    const float m = fmaxf(fmaxf(red[0], red[1]), fmaxf(red[2], red[3]));
    const float s = fmaxf(m, 1e-8f) * (1.f/127.f);
    sbc = 1.f / s;
    sw[row] = s;
  }
  __syncthreads();
  const float inv = sbc;
  char4 o;
  o.x = (char)__float2int_rn(v.x * inv); o.y = (char)__float2int_rn(v.y * inv);
  o.z = (char)__float2int_rn(v.z * inv); o.w = (char)__float2int_rn(v.w * inv);
  reinterpret_cast<char4*>(q + (size_t)row*D)[threadIdx.x] = o;
}

// ---------------------------------------------------------------------------
// h = rmsnorm(embed[idx], ln_in_w), f32 out. One block (256 thr) per row.
// ---------------------------------------------------------------------------
__global__ __launch_bounds__(256) void embed_rms_kernel(
    const int* __restrict__ idx, const float* __restrict__ embed,
    const float* __restrict__ g, float* __restrict__ h)
{
  const int row = blockIdx.x;
  const int tok = idx[row];
  const float4 xv = reinterpret_cast<const float4*>(embed + (size_t)tok*D)[threadIdx.x];
  float ss = xv.x*xv.x + xv.y*xv.y + xv.z*xv.z + xv.w*xv.w;
  #pragma unroll
  for (int off = 32; off > 0; off >>= 1) ss += __shfl_down(ss, off);
  __shared__ float red[4];
  if ((threadIdx.x & 63) == 0) red[threadIdx.x >> 6] = ss;
  __syncthreads();
  const float mean = (red[0]+red[1]+red[2]+red[3]) * (1.f/(float)D);
  const float rn = rsqrtf(mean + 1e-6f);
  const float4 gv = reinterpret_cast<const float4*>(g)[threadIdx.x];
  float4 ov;
  ov.x = xv.x*rn*gv.x; ov.y = xv.y*rn*gv.y; ov.z = xv.z*rn*gv.z; ov.w = xv.w*rn*gv.w;
  reinterpret_cast<float4*>(h + (size_t)row*D)[threadIdx.x] = ov;
}

// ---------------------------------------------------------------------------
// xn8 = i8-quantized rmsnorm(x, g) with per-row scale sx (fused, one pass).
// ---------------------------------------------------------------------------
__global__ __launch_bounds__(256) void rms_i8_kernel(
    const float* __restrict__ x, const float* __restrict__ g,
    char* __restrict__ q, float* __restrict__ sx)
{
  const int row = blockIdx.x;
  const float4 xv = reinterpret_cast<const float4*>(x + (size_t)row*D)[threadIdx.x];
  const float4 gv = reinterpret_cast<const float4*>(g)[threadIdx.x];
  float4 pv;
  pv.x = xv.x*gv.x; pv.y = xv.y*gv.y; pv.z = xv.z*gv.z; pv.w = xv.w*gv.w;
  float ss = xv.x*xv.x + xv.y*xv.y + xv.z*xv.z + xv.w*xv.w;
  float mg = fmaxf(fmaxf(fabsf(pv.x), fabsf(pv.y)), fmaxf(fabsf(pv.z), fabsf(pv.w)));
  #pragma unroll
  for (int off = 32; off > 0; off >>= 1) {
    ss += __shfl_down(ss, off);
    mg = fmaxf(mg, __shfl_down(mg, off));
  }
  __shared__ float reds[4], redm[4]; __shared__ float sbc;
  if ((threadIdx.x & 63) == 0) { reds[threadIdx.x >> 6] = ss; redm[threadIdx.x >> 6] = mg; }
  __syncthreads();
  if (threadIdx.x == 0) {
    const float mean = (reds[0]+reds[1]+reds[2]+reds[3]) * (1.f/(float)D);
    const float rn = rsqrtf(mean + 1e-6f);
    const float vmax = rn * fmaxf(fmaxf(redm[0], redm[1]), fmaxf(redm[2], redm[3]));
    const float s = fmaxf(vmax, 1e-8f) * (1.f/127.f);
    sx[row] = s;
    sbc = rn / s;
  }
  __syncthreads();
  const float f = sbc;
  char4 o;
  o.x = (char)__float2int_rn(pv.x * f); o.y = (char)__float2int_rn(pv.y * f);
  o.z = (char)__float2int_rn(pv.z * f); o.w = (char)__float2int_rn(pv.w * f);
  reinterpret_cast<char4*>(q + (size_t)row*D)[threadIdx.x] = o;
}

// ---------------------------------------------------------------------------
// Fused: h += p0 + p1; xn8 = i8 rmsnorm(h, g) + per-row scale sx.
// ---------------------------------------------------------------------------
__global__ __launch_bounds__(256) void rms_radd_i8_kernel(
    float* __restrict__ h, const float* __restrict__ p0,
    const float* __restrict__ p1, const float* __restrict__ g,
    char* __restrict__ q, float* __restrict__ sx)
{
  const int row = blockIdx.x;
  const size_t off = (size_t)row*D/4 + threadIdx.x;
  float4 hv = reinterpret_cast<const float4*>(h)[off];
  const float4 a = reinterpret_cast<const float4*>(p0)[off];
  const float4 b = reinterpret_cast<const float4*>(p1)[off];
  hv.x += a.x + b.x; hv.y += a.y + b.y; hv.z += a.z + b.z; hv.w += a.w + b.w;
  reinterpret_cast<float4*>(h)[off] = hv;
  const float4 gv = reinterpret_cast<const float4*>(g)[threadIdx.x];
  float4 pv;
  pv.x = hv.x*gv.x; pv.y = hv.y*gv.y; pv.z = hv.z*gv.z; pv.w = hv.w*gv.w;
  float ss = hv.x*hv.x + hv.y*hv.y + hv.z*hv.z + hv.w*hv.w;
  float mg = fmaxf(fmaxf(fabsf(pv.x), fabsf(pv.y)), fmaxf(fabsf(pv.z), fabsf(pv.w)));
  #pragma unroll
  for (int o2 = 32; o2 > 0; o2 >>= 1) {
    ss += __shfl_down(ss, o2);
    mg = fmaxf(mg, __shfl_down(mg, o2));
  }
  __shared__ float reds[4], redm[4]; __shared__ float sbc;
  if ((threadIdx.x & 63) == 0) { reds[threadIdx.x >> 6] = ss; redm[threadIdx.x >> 6] = mg; }
  __syncthreads();
  if (threadIdx.x == 0) {
    const float mean = (reds[0]+reds[1]+reds[2]+reds[3]) * (1.f/(float)D);
    const float rn = rsqrtf(mean + 1e-6f);
    const float vmax = rn * fmaxf(fmaxf(redm[0], redm[1]), fmaxf(redm[2], redm[3]));
    const float s = fmaxf(vmax, 1e-8f) * (1.f/127.f);
    sx[row] = s;
    sbc = rn / s;
  }
  __syncthreads();
  const float f = sbc;
  char4 o;
  o.x = (char)__float2int_rn(pv.x * f); o.y = (char)__float2int_rn(pv.y * f);
  o.z = (char)__float2int_rn(pv.z * f); o.w = (char)__float2int_rn(pv.w * f);
  reinterpret_cast<char4*>(q + (size_t)row*D)[threadIdx.x] = o;
}

// ---------------------------------------------------------------------------
// Per-row (len FFD=4096) i8 quantize of the FFN intermediate (f16 in).
// ---------------------------------------------------------------------------
__global__ __launch_bounds__(256) void quant_ffn_kernel(
    const f16* __restrict__ a, char* __restrict__ q, float* __restrict__ s)
{
  const int row = blockIdx.x;
  const size_t base = (size_t)row*(FFD/4);
  f16x4 v[4];
  float mx = 0.f;
  #pragma unroll
  for (int i = 0; i < 4; ++i) {
    v[i] = reinterpret_cast<const f16x4*>(a)[base + threadIdx.x + i*256];
    #pragma unroll
    for (int j = 0; j < 4; ++j) mx = fmaxf(mx, fabsf((float)v[i][j]));
  }
  #pragma unroll
  for (int off = 32; off > 0; off >>= 1) mx = fmaxf(mx, __shfl_down(mx, off));
  __shared__ float red[4]; __shared__ float sbc;
  if ((threadIdx.x & 63) == 0) red[threadIdx.x >> 6] = mx;
  __syncthreads();
  if (threadIdx.x == 0) {
    const float m = fmaxf(fmaxf(red[0], red[1]), fmaxf(red[2], red[3]));
    const float sr = fmaxf(m, 1e-8f) * (1.f/127.f);
    s[row] = sr;
    sbc = 1.f / sr;
  }
  __syncthreads();
  const float inv = sbc;
  #pragma unroll
  for (int i = 0; i < 4; ++i) {
    char4 o;
    o.x = (char)__float2int_rn((float)v[i][0] * inv);
    o.y = (char)__float2int_rn((float)v[i][1] * inv);
    o.z = (char)__float2int_rn((float)v[i][2] * inv);
    o.w = (char)__float2int_rn((float)v[i][3] * inv);
    reinterpret_cast<char4*>(q)[base + threadIdx.x + i*256] = o;
  }
}

// ---------------------------------------------------------------------------
// Time-mix recurrence: chunked prefix sum over T.
// ---------------------------------------------------------------------------
__global__ __launch_bounds__(256) void scan1_kernel(
    const float* __restrict__ k, const float* __restrict__ v, int ld,
    const float* __restrict__ decay, float* __restrict__ part)
{
  const int d = blockIdx.x*256 + threadIdx.x;
  const int c = blockIdx.y, b = blockIdx.z;
  const float dec = 1.f / (1.f + expf(-decay[d]));
  const float ldc = logf(fmaxf(dec, 1e-7f));
  float sum = 0.f;
  const int row0 = b*T + c*CT;
  #pragma unroll 4
  for (int t = 0; t < CT; ++t) {
    const size_t i = (size_t)(row0 + t)*ld + d;
    const float scale = expf((float)(c*CT + t) * ldc);
    sum += (k[i] * v[i]) / fmaxf(scale, 1e-10f);
  }
  part[((size_t)b*NT + c)*D + d] = sum;
}

__global__ __launch_bounds__(256) void scan23_kernel(
    const float* __restrict__ r, const float* __restrict__ k,
    const float* __restrict__ v, int ld, const float* __restrict__ decay,
    const float* __restrict__ part, float* __restrict__ rs)
{
  const int d = blockIdx.x*256 + threadIdx.x;
  const int c = blockIdx.y, b = blockIdx.z;
  const float dec = 1.f / (1.f + expf(-decay[d]));
  const float ldc = logf(fmaxf(dec, 1e-7f));
  float cum = 0.f;
  for (int j = 0; j < c; ++j) cum += part[((size_t)b*NT + j)*D + d];
  const int row0 = b*T + c*CT;
  #pragma unroll 4
  for (int t = 0; t < CT; ++t) {
    const size_t i = (size_t)(row0 + t)*ld + d;
    const float scale = expf((float)(c*CT + t) * ldc);
    cum += (k[i] * v[i]) / fmaxf(scale, 1e-10f);
    rs[(size_t)(row0 + t)*D + d] = r[i] * (cum * scale);
  }
}

// fallback-path kernels -------------------------------------------------------
__global__ __launch_bounds__(256) void rms_f16_kernel(
    const float* __restrict__ x, const float* __restrict__ g, f16* __restrict__ o)
{
  const int row = blockIdx.x;
  const float4 xv = reinterpret_cast<const float4*>(x + (size_t)row*D)[threadIdx.x];
  float ss = xv.x*xv.x + xv.y*xv.y + xv.z*xv.z + xv.w*xv.w;
  #pragma unroll
  for (int off = 32; off > 0; off >>= 1) ss += __shfl_down(ss, off);
  __shared__ float red[4];
  if ((threadIdx.x & 63) == 0) red[threadIdx.x >> 6] = ss;
  __syncthreads();
  const float mean = (red[0]+red[1]+red[2]+red[3]) * (1.f/(float)D);
  const float rn = rsqrtf(mean + 1e-6f);
  const float4 gv = reinterpret_cast<const float4*>(g)[threadIdx.x];
  f16x4 ov;
  ov[0] = (f16)(xv.x*rn*gv.x); ov[1] = (f16)(xv.y*rn*gv.y);
  ov[2] = (f16)(xv.z*rn*gv.z); ov[3] = (f16)(xv.w*rn*gv.w);
  reinterpret_cast<f16x4*>(o + (size_t)row*D)[threadIdx.x] = ov;
}

__global__ __launch_bounds__(256) void scan2_kernel(float* __restrict__ part)
{
  const int d = blockIdx.x*256 + threadIdx.x;
  const int b = blockIdx.y;
  float run = 0.f;
  #pragma unroll 8
  for (int c = 0; c < NT; ++c) {
    const size_t i = ((size_t)b*NT + c)*D + d;
    const float t = part[i];
    part[i] = run;
    run += t;
  }
}

__global__ __launch_bounds__(256) void scan3_kernel(
    const float* __restrict__ r, const float* __restrict__ k,
    const float* __restrict__ v, int ld, const float* __restrict__ decay,
    const float* __restrict__ part, float* __restrict__ rs)
{
  const int d = blockIdx.x*256 + threadIdx.x;
  const int c = blockIdx.y, b = blockIdx.z;
  const float dec = 1.f / (1.f + expf(-decay[d]));
  const float ldc = logf(fmaxf(dec, 1e-7f));
  float cum = part[((size_t)b*NT + c)*D + d];
  const int row0 = b*T + c*CT;
  #pragma unroll 4
  for (int t = 0; t < CT; ++t) {
    const size_t i = (size_t)(row0 + t)*ld + d;
    const float scale = expf((float)(c*CT + t) * ldc);
    cum += (k[i] * v[i]) / fmaxf(scale, 1e-10f);
    rs[(size_t)(row0 + t)*D + d] = r[i] * (cum * scale);
  }
}

__global__ __launch_bounds__(256) void silumul_kernel(
    const f16* __restrict__ a, const f16* __restrict__ b, f16* __restrict__ o, int n4)
{
  const int i = blockIdx.x*256 + threadIdx.x;
  if (i >= n4) return;
  const f16x4 av = reinterpret_cast<const f16x4*>(a)[i];
  const f16x4 bv = reinterpret_cast<const f16x4*>(b)[i];
  f16x4 ov;
  #pragma unroll
  for (int j = 0; j < 4; ++j) {
    const float x = (float)av[j];
    ov[j] = (f16)((x / (1.f + expf(-x))) * (float)bv[j]);
  }
  reinterpret_cast<f16x4*>(o)[i] = ov;
}

// ---------------------------------------------------------------------------
// XCD-chunked bijective block swizzle (m204).
// ---------------------------------------------------------------------------
__device__ __forceinline__ int xcd_swizzle(int fid, int nwg) {
  const int q = nwg >> 3, r = nwg & 7, x = fid & 7, o = fid >> 3;
  return (x < r ? x*(q+1) : r*(q+1) + (x-r)*q) + o;
}

// ---------------------------------------------------------------------------
// RING GEMM, INT8 (r11-proven): 3-buffer, depth-2 prefetch, counted vmcnt,
// ONE barrier/K-step. K-step 64, mfma_i32_16x16x64_i8.
// out[M,N] = epi( sx[row] * scl[col] * (A8 @ W8^T) ), f32 out. BN=128.
// EPI: 0 none, 2 +resid, 3 sigmoid iff col<D.
// SPLITK: gridDim.z pieces write outp + z*M*N.
// ---------------------------------------------------------------------------
template<int BM, int NW, int EPI, bool SPLITK = false>
__global__ __launch_bounds__(NW*64) void gemm_i8_kernel(
    const char* __restrict__ A, const char* __restrict__ Bq,
    const float* __restrict__ sx, const float* __restrict__ scl,
    const float* __restrict__ resid, float* __restrict__ outp, int N, int K)
{
  constexpr int WN = 2;
  constexpr int WM = NW / WN;
  constexpr int MF = BM / (WM*16);
  constexpr int ACALLS = BM / (16*NW);
  constexpr int BCALLS = 128 / (16*NW);
  constexpr int VCNT = ACALLS + BCALLS;
  __shared__ __align__(16) char As[3][BM*64];
  __shared__ __align__(16) char Bs[3][128*64];

  const int tid = threadIdx.x;
  const int wave = tid >> 6, lane = tid & 63;
  const int gx = gridDim.x, nwg = gx * gridDim.y;
  const int wg = xcd_swizzle(blockIdx.x + blockIdx.y*gx, nwg);
  const int m0 = (wg % gx) * BM, n0 = (wg / gx) * 128;
  const int lr = lane & 15, kg = lane >> 4;
  const int wm0 = (wave / WN) * (MF*16), wn0 = (wave % WN) * 64;
  const int grow = lane >> 2;
  const int gcol = (lane & 3) * 16;
  const char* Ab = A  + (size_t)(m0 + grow)*K + gcol;
  const char* Bb = Bq + (size_t)(n0 + grow)*K + gcol;

  int kbeg = 0, kend = K;
  size_t obase = 0;
  if (SPLITK) {
    const int kc = K / gridDim.z;
    kbeg = blockIdx.z * kc; kend = kbeg + kc;
    obase = (size_t)blockIdx.z * M * (size_t)N;
  }
  const int NKT = (kend - kbeg) / 64;

  auto stage = [&](int buf, int k0) {
    #pragma unroll
    for (int c = 0; c < ACALLS; ++c) {
      const int rb = (c*NW + wave) * 16;
      gload16b(Ab + (size_t)rb*K + k0, &As[buf][rb*64]);
    }
    #pragma unroll
    for (int c = 0; c < BCALLS; ++c) {
      const int rb = (c*NW + wave) * 16;
      gload16b(Bb + (size_t)rb*K + k0, &Bs[buf][rb*64]);
    }
  };

  i32x4 acc[MF][4] = {};
  stage(0, kbeg);
  stage(1, kbeg + 64);

  int cur = 0;
  for (int t = 0; t < NKT; ++t) {
    vm_wait<VCNT>();
    ring_barrier();
    if (t + 2 < NKT) {
      int nb = cur + 2; if (nb >= 3) nb -= 3;
      stage(nb, kbeg + (t + 2) * 64);
    }
    i32x4 af[MF], bf[4];
    #pragma unroll
    for (int i = 0; i < MF; ++i)
      af[i] = *reinterpret_cast<const i32x4*>(&As[cur][(wm0 + i*16 + lr)*64 + kg*16]);
    #pragma unroll
    for (int j = 0; j < 4; ++j)
      bf[j] = *reinterpret_cast<const i32x4*>(&Bs[cur][(wn0 + j*16 + lr)*64 + kg*16]);
    #pragma unroll
    for (int i = 0; i < MF; ++i)
      #pragma unroll
      for (int j = 0; j < 4; ++j)
        acc[i][j] = __builtin_amdgcn_mfma_i32_16x16x64_i8(af[i], bf[j], acc[i][j], 0, 0, 0);
    ++cur; if (cur == 3) cur = 0;
  }

  // C/D frag layout: col=lane&15, row=(lane>>4)*4+e (dtype-independent)
  #pragma unroll
  for (int j = 0; j < 4; ++j) {
    const int col = n0 + wn0 + j*16 + lr;
    const float sv = scl[col];
    #pragma unroll
    for (int i = 0; i < MF; ++i) {
      #pragma unroll
      for (int e = 0; e < 4; ++e) {
        const int row = m0 + wm0 + i*16 + kg*4 + e;
        float y = (float)acc[i][j][e] * sx[row] * sv;
        if (EPI == 3 && col < D) y = 1.f / (1.f + expf(-y));
        if (EPI == 2) y += resid[(size_t)row*N + col];
        outp[obase + (size_t)row*N + col] = y;
      }
    }
  }
}

// ---------------------------------------------------------------------------
// RING HEAD GEMM, INT8 (r11-proven): 128x256 tile, 8 waves, K-step 64.
// ---------------------------------------------------------------------------
__global__ __launch_bounds__(512) void gemm_head_i8_kernel(
    const char* __restrict__ A, const char* __restrict__ Bq,
    const float* __restrict__ sx, const float* __restrict__ sw,
    float* __restrict__ out, int N, int K)
{
  constexpr int BM = 128, BN = 256;
  __shared__ __align__(16) char As[3][BM*64];
  __shared__ __align__(16) char Bs[3][BN*64];
  const int tid = threadIdx.x;
  const int wave = tid >> 6, lane = tid & 63;
  const int gx = gridDim.x, nwg = gx * gridDim.y;
  const int wg = xcd_swizzle(blockIdx.x + blockIdx.y*gx, nwg);
  const int m0 = (wg % gx) * BM, n0 = (wg / gx) * BN;
  const int lr = lane & 15, kg = lane >> 4;
  const int wm0 = (wave >> 2) * 64, wn0 = (wave & 3) * 64;
  const int grow = lane >> 2;
  const int gcol = (lane & 3) * 16;
  const char* Ab = A  + (size_t)(m0 + grow)*K + gcol;
  const char* Bb = Bq + (size_t)(n0 + grow)*K + gcol;

  auto stage = [&](int buf, int k0) {
    gload16b(Ab + (size_t)(wave*16)*K + k0, &As[buf][(wave*16)*64]);
    gload16b(Bb + (size_t)(wave*16)*K + k0, &Bs[buf][(wave*16)*64]);
    gload16b(Bb + (size_t)((wave+8)*16)*K + k0, &Bs[buf][((wave+8)*16)*64]);
  };

  i32x4 acc[4][4] = {};
  stage(0, 0);
  stage(1, 64);

  const int NKT = K / 64;
  int cur = 0;
  for (int t = 0; t < NKT; ++t) {
    vm_wait<3>();
    ring_barrier();
    if (t + 2 < NKT) {
      int nb = cur + 2; if (nb >= 3) nb -= 3;
      stage(nb, (t + 2) * 64);
    }
    i32x4 af[4], bf[4];
    #pragma unroll
    for (int i = 0; i < 4; ++i)
      af[i] = *reinterpret_cast<const i32x4*>(&As[cur][(wm0 + i*16 + lr)*64 + kg*16]);
    #pragma unroll
    for (int j = 0; j < 4; ++j)
      bf[j] = *reinterpret_cast<const i32x4*>(&Bs[cur][(wn0 + j*16 + lr)*64 + kg*16]);
    #pragma unroll
    for (int i = 0; i < 4; ++i)
      #pragma unroll
      for (int j = 0; j < 4; ++j)
        acc[i][j] = __builtin_amdgcn_mfma_i32_16x16x64_i8(af[i], bf[j], acc[i][j], 0, 0, 0);
    ++cur; if (cur == 3) cur = 0;
  }
  #pragma unroll
  for (int j = 0; j < 4; ++j) {
    const int col = n0 + wn0 + j*16 + lr;
    const float scw = sw[col];
    #pragma unroll
    for (int i = 0; i < 4; ++i) {
      #pragma unroll
      for (int e = 0; e < 4; ++e) {
        const int row = m0 + wm0 + i*16 + kg*4 + e;
        out[(size_t)row*N + col] = (float)acc[i][j][e] * sx[row] * scw;
      }
    }
  }
}

// ---------------------------------------------------------------------------
// RING FUSED FFN GEMM, INT8 (r11-proven): g16 = (f16)( silu(.)*(.) ).
// 128x128 tile, 8 waves, ring-3, K-step 64.
// ---------------------------------------------------------------------------
__global__ __launch_bounds__(512) void gemm_ffn_i8_kernel(
    const char* __restrict__ A, const char* __restrict__ B1, const char* __restrict__ B2,
    const float* __restrict__ sx, const float* __restrict__ s1, const float* __restrict__ s2,
    f16* __restrict__ outg, int N, int K)
{
  constexpr int BM = 128, BN = 128;
  __shared__ __align__(16) char As [3][BM*64];
  __shared__ __align__(16) char B1s[3][BN*64];
  __shared__ __align__(16) char B2s[3][BN*64];
  const int tid = threadIdx.x;
  const int wave = tid >> 6, lane = tid & 63;
  const int gx = gridDim.x, nwg = gx * gridDim.y;
  const int wg = xcd_swizzle(blockIdx.x + blockIdx.y*gx, nwg);
  const int m0 = (wg % gx) * BM, n0 = (wg / gx) * BN;
  const int lr = lane & 15, kg = lane >> 4;
  const int wm0 = (wave >> 1) * 32, wn0 = (wave & 1) * 64;  // 8 waves: 4M x 2N
  const int grow = lane >> 2;
  const int gcol = (lane & 3) * 16;
  const char* Ab  = A  + (size_t)(m0 + grow)*K + gcol;
  const char* B1b = B1 + (size_t)(n0 + grow)*K + gcol;
  const char* B2b = B2 + (size_t)(n0 + grow)*K + gcol;

  auto stage = [&](int buf, int k0) {
    const int rb = wave * 16;
    gload16b(Ab  + (size_t)rb*K + k0, &As [buf][rb*64]);
    gload16b(B1b + (size_t)rb*K + k0, &B1s[buf][rb*64]);
    gload16b(B2b + (size_t)rb*K + k0, &B2s[buf][rb*64]);
  };

  i32x4 aca[2][4] = {};
  i32x4 acb[2][4] = {};
  stage(0, 0);
  stage(1, 64);

  const int NKT = K / 64;
  int cur = 0;
  for (int t = 0; t < NKT; ++t) {
    vm_wait<3>();
    ring_barrier();
    if (t + 2 < NKT) {
      int nb = cur + 2; if (nb >= 3) nb -= 3;
      stage(nb, (t + 2) * 64);
    }
    i32x4 af[2], b1f[4], b2f[4];
    #pragma unroll
    for (int i = 0; i < 2; ++i)
      af[i] = *reinterpret_cast<const i32x4*>(&As[cur][(wm0 + i*16 + lr)*64 + kg*16]);
    #pragma unroll
    for (int j = 0; j < 4; ++j) {
      b1f[j] = *reinterpret_cast<const i32x4*>(&B1s[cur][(wn0 + j*16 + lr)*64 + kg*16]);
      b2f[j] = *reinterpret_cast<const i32x4*>(&B2s[cur][(wn0 + j*16 + lr)*64 + kg*16]);
    }
    #pragma unroll
    for (int i = 0; i < 2; ++i)
      #pragma unroll
      for (int j = 0; j < 4; ++j) {
        aca[i][j] = __builtin_amdgcn_mfma_i32_16x16x64_i8(af[i], b1f[j], aca[i][j], 0, 0, 0);
        acb[i][j] = __builtin_amdgcn_mfma_i32_16x16x64_i8(af[i], b2f[j], acb[i][j], 0, 0, 0);
      }
    ++cur; if (cur == 3) cur = 0;
  }
  #pragma unroll
  for (int j = 0; j < 4; ++j) {
    const int col = n0 + wn0 + j*16 + lr;
    const float sa = s1[col], sb = s2[col];
    #pragma unroll
    for (int i = 0; i < 2; ++i) {
      #pragma unroll
      for (int e = 0; e < 4; ++e) {
        const int row = m0 + wm0 + i*16 + kg*4 + e;
        const float srow = sx[row];
        const float a = (float)aca[i][j][e] * srow * sa;
        const float b = (float)acb[i][j][e] * srow * sb;
        outg[(size_t)row*N + col] = (f16)((a / (1.f + expf(-a))) * b);
      }
    }
  }
}

// ---------------------------------------------------------------------------
// FALLBACK GEMM: inline quantize from f32 weights (used if ws too small).
// ---------------------------------------------------------------------------
__global__ __launch_bounds__(64) void scales_kernel(
    const float* __restrict__ Wr, const float* __restrict__ Wk,
    const float* __restrict__ Wv, const float* __restrict__ Wo,
    const float* __restrict__ W1, const float* __restrict__ W2,
    const float* __restrict__ Woc, float* __restrict__ s)
{
  const int r = blockIdx.x, l = blockIdx.y;
  const float* base; int len;
  if (r < 4*D) {
    const int m = r >> 10, row = r & (D-1);
    const float* Wm = (m==0) ? Wr : (m==1) ? Wk : (m==2) ? Wv : Wo;
    base = Wm + (size_t)l*D*D + (size_t)row*D; len = D;
  } else if (r < 4*D + 2*FFD) {
    int row = r - 4*D;
    const float* Wm = (row < FFD) ? W1 : W2;
    if (row >= FFD) row -= FFD;
    base = Wm + (size_t)l*FFD*D + (size_t)row*D; len = D;
  } else {
    const int row = r - (4*D + 2*FFD);
    base = Woc + (size_t)l*D*FFD + (size_t)row*FFD; len = FFD;
  }
  float sum = 0.f;
  for (int i = threadIdx.x; i < len; i += 64) sum += fabsf(base[i]);
  #pragma unroll
  for (int off = 32; off > 0; off >>= 1) sum += __shfl_down(sum, off);
  if (threadIdx.x == 0)
    s[(size_t)l*ROWS_PER_LAYER + r] = fmaxf(sum / (float)len, 1e-5f);
}

template<int BM, int EPI, bool QUANT, bool OUTF16>
__global__ __launch_bounds__(256) void gemm_bt_kernel(
    const f16* __restrict__ A, const float* __restrict__ Bw,
    const float* __restrict__ scl, const float* __restrict__ resid,
    void* __restrict__ outp, int N, int K)
{
  constexpr int BN = 128, LDT = 40;
  constexpr int MF = (BM == 128) ? 4 : 2;
  __shared__ f16 As[BM*LDT];
  __shared__ f16 Bs[BN*LDT];
  const int tid = threadIdx.x;
  const int m0 = blockIdx.y * BM, n0 = blockIdx.x * BN;
  const int wave = tid >> 6, lane = tid & 63;
  const int lr = lane & 15, kg = lane >> 4;
  const int wm0 = (wave >> 1) * (MF*16), wn0 = (wave & 1) * 64;
  f32x4 acc[MF][4] = {};
  for (int k0 = 0; k0 < K; k0 += 32) {
    #pragma unroll
    for (int c = 0; c < (BM*4)/256; ++c) {
      const int chunk = tid + c*256;
      const int row = chunk >> 2, c8 = (chunk & 3) << 3;
      *reinterpret_cast<f16x8*>(&As[row*LDT + c8]) =
        *reinterpret_cast<const f16x8*>(A + (size_t)(m0+row)*K + k0 + c8);
    }
    #pragma unroll
    for (int c = 0; c < 2; ++c) {
      const int chunk = tid + c*256;
      const int row = chunk >> 2, c8 = (chunk & 3) << 3;
      const float* bp = Bw + (size_t)(n0+row)*K + k0 + c8;
      const float4 f0 = *reinterpret_cast<const float4*>(bp);
      const float4 f1 = *reinterpret_cast<const float4*>(bp + 4);
      const float wv[8] = {f0.x,f0.y,f0.z,f0.w,f1.x,f1.y,f1.z,f1.w};
      f16x8 qv;
      if (QUANT) {
        const float hs = 0.5f * scl[n0+row];
        #pragma unroll
        for (int j = 0; j < 8; ++j)
          qv[j] = wv[j] > hs ? (f16)1.f : (wv[j] < -hs ? (f16)(-1.f) : (f16)0.f);
      } else {
        #pragma unroll
        for (int j = 0; j < 8; ++j) qv[j] = (f16)wv[j];
      }
      *reinterpret_cast<f16x8*>(&Bs[row*LDT + c8]) = qv;
    }
    __syncthreads();
    f16x8 af[MF], bf[4];
    #pragma unroll
    for (int i = 0; i < MF; ++i)
      af[i] = *reinterpret_cast<const f16x8*>(&As[(wm0 + i*16 + lr)*LDT + kg*8]);
    #pragma unroll
    for (int j = 0; j < 4; ++j)
      bf[j] = *reinterpret_cast<const f16x8*>(&Bs[(wn0 + j*16 + lr)*LDT + kg*8]);
    #pragma unroll
    for (int i = 0; i < MF; ++i)
      #pragma unroll
      for (int j = 0; j < 4; ++j)
        acc[i][j] = __builtin_amdgcn_mfma_f32_16x16x32_f16(af[i], bf[j], acc[i][j], 0, 0, 0);
    __syncthreads();
  }
  #pragma unroll
  for (int j = 0; j < 4; ++j) {
    const int col = n0 + wn0 + j*16 + lr;
    const float sv = QUANT ? scl[col] : 1.f;
    #pragma unroll
    for (int i = 0; i < MF; ++i) {
      #pragma unroll
      for (int e = 0; e < 4; ++e) {
        const int row = m0 + wm0 + i*16 + kg*4 + e;
        float y = acc[i][j][e] * sv;
        if (EPI == 1) y = 1.f / (1.f + expf(-y));
        if (EPI == 2) y += resid[(size_t)row*N + col];
        if (OUTF16) reinterpret_cast<f16*>(outp)[(size_t)row*N + col] = (f16)y;
        else        reinterpret_cast<float*>(outp)[(size_t)row*N + col] = y;
      }
    }
  }
}

// ---------------------------------------------------------------------------
extern "C" void kernel_launch(void* const* d_in, const int* in_sizes, int n_in,
                              void* d_out, int out_size, void* d_ws, size_t ws_size,
                              hipStream_t stream)
{
  (void)in_sizes; (void)n_in; (void)out_size;
  const int*   idx      = (const int*)  d_in[0];
  const float* embed    = (const float*)d_in[1];
  const float* ln_in_w  = (const float*)d_in[2];
  const float* ln1_w    = (const float*)d_in[3];
  const float* Wr       = (const float*)d_in[4];
  const float* Wk       = (const float*)d_in[5];
  const float* Wv       = (const float*)d_in[6];
  const float* Wo_t     = (const float*)d_in[7];
  const float* decay    = (const float*)d_in[8];
  const float* lnx_w    = (const float*)d_in[9];
  const float* ln2_w    = (const float*)d_in[10];
  const float* W1       = (const float*)d_in[11];
  const float* W2       = (const float*)d_in[12];
  const float* Wo_c     = (const float*)d_in[13];
  const float* ln_out_w = (const float*)d_in[14];
  float* out = (float*)d_out;

  char* p = (char*)d_ws;
  auto alloc = [&](size_t bytes) { void* q = (void*)p; p += (bytes + 255) & ~(size_t)255; return q; };
  float* h      = (float*)alloc((size_t)M*D*sizeof(float));
  f16*   xn     = (f16*)  alloc((size_t)M*D*sizeof(f16));       // fallback only
  float* rkv    = (float*)alloc((size_t)M*RKV*sizeof(float));   // r|k|v; reused as split-K partials
  float* rsb    = (float*)alloc((size_t)M*D*sizeof(float));
  f16*   abf    = (f16*)  alloc((size_t)M*FFD*sizeof(f16));
  f16*   bbf    = (f16*)  alloc((size_t)M*FFD*sizeof(f16));     // fallback only
  float* scales = (float*)alloc((size_t)NL*ROWS_PER_LAYER*sizeof(float));
  float* part   = (float*)alloc((size_t)BB*NT*D*sizeof(float));
  const size_t base_need = (size_t)(p - (char*)d_ws);
  const size_t fast_need = base_need + (NL*QL + 256)
      + ((size_t)V*D + 256) + (V*sizeof(float) + 256)
      + ((size_t)M*D + 256) + (M*sizeof(float) + 256)
      + ((size_t)M*FFD + 256) + (M*sizeof(float) + 256);

  embed_rms_kernel<<<M, 256, 0, stream>>>(idx, embed, ln_in_w, h);

  const dim3 gS(D/256, NT, BB);   // scan1/scan23: 512 blocks
  const dim3 gS2(D/256, BB);      // scan2 (fallback): 8 blocks

  if (ws_size >= fast_need) {
    // ================= FAST PATH: i8 weights + i8 activations =================
    char*  qw8  = (char*) alloc(NL*QL);
    char*  emb8 = (char*) alloc((size_t)V*D);
    float* sw   = (float*)alloc((size_t)V*sizeof(float));
    char*  xn8  = (char*) alloc((size_t)M*D);
    float* sx   = (float*)alloc((size_t)M*sizeof(float));
    char*  abf8 = (char*) alloc((size_t)M*FFD);
    float* sax  = (float*)alloc((size_t)M*sizeof(float));
    quant_kernel<<<dim3(ROWS_PER_LAYER, NL), 256, 0, stream>>>(Wr, Wk, Wv, Wo_t, W1, W2, Wo_c, qw8, scales);
    quant_embed_kernel<<<V, 256, 0, stream>>>(embed, emb8, sw);

    const dim3 gRKV(M/128, RKV/128);     // 16 x 24 = 384 blocks, 8 waves
    const dim3 gO(M/64, D/128);          // 32 x 8  = 256 blocks, 4 waves
    const dim3 gOC(M/64, D/128, 2);      // 512 blocks (split-K x2)
    const dim3 gFFN(M/128, FFD/128);     // 16 x 32 = 512 blocks, 8 waves
    const dim3 gHEAD(M/128, V/256);      // 16 x 125 = 2000 blocks, 8 waves

    rms_i8_kernel<<<M, 256, 0, stream>>>(h, ln1_w, xn8, sx);   // first layer's ln1
    for (int l = 0; l < NL; ++l) {
      const float* sl = scales + (size_t)l*ROWS_PER_LAYER;
      const char* qb = qw8 + (size_t)l*QL;
      const char *qrkv = qb, *qo = qb + 3ull*D*D;
      const char *q1 = qb + 4ull*D*D, *q2 = qb + 4ull*D*D + (size_t)FFD*D;
      const char *qoc = qb + 4ull*D*D + 2ull*(size_t)FFD*D;
      const float* dcy = decay + (size_t)l*D;
      // ---- time mix ----
      gemm_i8_kernel<128,8,3><<<gRKV, 512, 0, stream>>>(xn8, qrkv, sx, sl, nullptr, rkv, RKV, D);
      scan1_kernel<<<gS, 256, 0, stream>>>(rkv + D, rkv + 2*D, RKV, dcy, part);
      scan23_kernel<<<gS, 256, 0, stream>>>(rkv, rkv + D, rkv + 2*D, RKV, dcy, part, rsb);
      rms_i8_kernel<<<M, 256, 0, stream>>>(rsb, lnx_w + (size_t)l*D, xn8, sx);
      gemm_i8_kernel<64,4,2><<<gO, 256, 0, stream>>>(xn8, qo, sx, sl + 3*D, h, h, D, D);
      // ---- channel mix ----
      rms_i8_kernel<<<M, 256, 0, stream>>>(h, ln2_w + (size_t)l*D, xn8, sx);
      gemm_ffn_i8_kernel<<<gFFN, 512, 0, stream>>>(xn8, q1, q2, sx, sl + 4*D, sl + 4*D + FFD, abf, FFD, D);
      quant_ffn_kernel<<<M, 256, 0, stream>>>(abf, abf8, sax);
      gemm_i8_kernel<64,4,0,true><<<gOC, 256, 0, stream>>>(abf8, qoc, sax, sl + 4*D + 2*FFD, nullptr, rkv, D, FFD);
      const float* gnext = (l + 1 < NL) ? (ln1_w + (size_t)(l+1)*D) : ln_out_w;
      rms_radd_i8_kernel<<<M, 256, 0, stream>>>(h, rkv, rkv + (size_t)M*D, gnext, xn8, sx);
    }
    // ---- weight-tied head (A already i8 from last rms_radd) ----
    gemm_head_i8_kernel<<<gHEAD, 512, 0, stream>>>(xn8, emb8, sx, sw, out, V, D);
  } else {
    // ================= FALLBACK: inline-quant f16 path =================
    float* rbuf = rkv;
    float* kbuf = rkv + (size_t)M*D;
    float* vbuf = rkv + 2ull*M*D;
    scales_kernel<<<dim3(ROWS_PER_LAYER, NL), 64, 0, stream>>>(Wr, Wk, Wv, Wo_t, W1, W2, Wo_c, scales);
    const dim3 gD(D/128, M/64);
    const dim3 gF(FFD/128, M/128);
    for (int l = 0; l < NL; ++l) {
      const float* sl = scales + (size_t)l*ROWS_PER_LAYER;
      const float* dcy = decay + (size_t)l*D;
      rms_f16_kernel<<<M, 256, 0, stream>>>(h, ln1_w + (size_t)l*D, xn);
      gemm_bt_kernel<64,1,true,false><<<gD, 256, 0, stream>>>(xn, Wr + (size_t)l*D*D, sl,       nullptr, rbuf, D, D);
      gemm_bt_kernel<64,0,true,false><<<gD, 256, 0, stream>>>(xn, Wk + (size_t)l*D*D, sl + D,   nullptr, kbuf, D, D);
      gemm_bt_kernel<64,0,true,false><<<gD, 256, 0, stream>>>(xn, Wv + (size_t)l*D*D, sl + 2*D, nullptr, vbuf, D, D);
      scan1_kernel<<<gS, 256, 0, stream>>>(kbuf, vbuf, D, dcy, part);
      scan2_kernel<<<gS2, 256, 0, stream>>>(part);
      scan3_kernel<<<gS, 256, 0, stream>>>(rbuf, kbuf, vbuf, D, dcy, part, rsb);
      rms_f16_kernel<<<M, 256, 0, stream>>>(rsb, lnx_w + (size_t)l*D, xn);
      gemm_bt_kernel<64,2,true,false><<<gD, 256, 0, stream>>>(xn, Wo_t + (size_t)l*D*D, sl + 3*D, h, h, D, D);
      rms_f16_kernel<<<M, 256, 0, stream>>>(h, ln2_w + (size_t)l*D, xn);
      gemm_bt_kernel<128,0,true,true><<<gF, 256, 0, stream>>>(xn, W1 + (size_t)l*FFD*D, sl + 4*D,       nullptr, abf, FFD, D);
      gemm_bt_kernel<128,0,true,true><<<gF, 256, 0, stream>>>(xn, W2 + (size_t)l*FFD*D, sl + 4*D + FFD, nullptr, bbf, FFD, D);
      silumul_kernel<<<(M*FFD/4)/256, 256, 0, stream>>>(abf, bbf, abf, M*FFD/4);
      gemm_bt_kernel<64,2,true,false><<<gD, 256, 0, stream>>>(abf, Wo_c + (size_t)l*D*FFD, sl + 4*D + 2*FFD, h, h, D, FFD);
    }
    rms_f16_kernel<<<M, 256, 0, stream>>>(h, ln_out_w, xn);
    gemm_bt_kernel<128,0,false,false><<<dim3(V/128, M/128), 256, 0, stream>>>(xn, embed, nullptr, nullptr, out, V, D);
  }
}

// Round 14
// 1131.922 us; speedup vs baseline: 1.0790x; 1.0524x over previous
//
#include <hip/hip_runtime.h>

typedef _Float16 f16;
typedef _Float16 f16x8 __attribute__((ext_vector_type(8)));
typedef _Float16 f16x4 __attribute__((ext_vector_type(4)));
typedef float f32x4 __attribute__((ext_vector_type(4)));
typedef int i32x4 __attribute__((ext_vector_type(4)));

static constexpr int BB = 2, T = 1024, D = 1024, FFD = 4096, V = 32000, NL = 6;
static constexpr int M = BB * T;                       // 2048 rows
static constexpr int ROWS_PER_LAYER = 4*D + 2*FFD + D; // 13312 scale rows per layer
static constexpr size_t QL = 4ull*D*D + 2ull*FFD*D + (size_t)D*FFD; // 16.78M elems/layer
static constexpr int NT = 64, CT = T / NT;             // scan: 64 chunks x 16 steps
static constexpr int RKV = 3*D;                        // fused rkv row stride

// direct global->LDS, 16B per lane. lds base wave-uniform; HW writes lane i at
// lds + i*16 (m104).
__device__ __forceinline__ void gload16b(const void* g, void* l) {
  __builtin_amdgcn_global_load_lds(
      (const __attribute__((address_space(1))) void*)g,
      (__attribute__((address_space(3))) void*)l, 16, 0, 0);
}
// counted vmcnt wait: allow the newest stage's N loads to remain in flight.
template<int N> __device__ __forceinline__ void vm_wait() {
  static_assert(N >= 2 && N <= 4, "unsupported vmcnt");
  if constexpr (N == 2) asm volatile("s_waitcnt vmcnt(2)" ::: "memory");
  else if constexpr (N == 3) asm volatile("s_waitcnt vmcnt(3)" ::: "memory");
  else                       asm volatile("s_waitcnt vmcnt(4)" ::: "memory");
}
// ring-phase boundary: all waves' reads of the oldest buffer are complete;
// sched_barrier pins the next stage AFTER the barrier.
__device__ __forceinline__ void ring_barrier() {
  __builtin_amdgcn_s_barrier();
  __builtin_amdgcn_sched_barrier(0);
}

// ---------------------------------------------------------------------------
// Single-pass per-row scale + ternary-quantize to i8 (EXACT: w_q in {-1,0,1}).
// qw layout per layer: [qr(D,D) qk qv qo | q1(FFD,D) q2 | qoc(D,FFD)]
// ---------------------------------------------------------------------------
__global__ __launch_bounds__(256) void quant_kernel(
    const float* __restrict__ Wr, const float* __restrict__ Wk,
    const float* __restrict__ Wv, const float* __restrict__ Wo,
    const float* __restrict__ W1, const float* __restrict__ W2,
    const float* __restrict__ Woc, char* __restrict__ qw, float* __restrict__ scales)
{
  const int r = blockIdx.x, l = blockIdx.y;
  const float* base; int len; size_t dst;
  if (r < 4*D) {
    const int m = r >> 10, row = r & (D-1);
    const float* Wm = (m==0) ? Wr : (m==1) ? Wk : (m==2) ? Wv : Wo;
    base = Wm + (size_t)l*D*D + (size_t)row*D; len = D;
    dst = (size_t)l*QL + (size_t)m*D*D + (size_t)row*D;
  } else if (r < 4*D + 2*FFD) {
    int row = r - 4*D;
    const int m = row >= FFD; if (m) row -= FFD;
    const float* Wm = m ? W2 : W1;
    base = Wm + (size_t)l*FFD*D + (size_t)row*D; len = D;
    dst = (size_t)l*QL + 4ull*D*D + (size_t)m*FFD*D + (size_t)row*D;
  } else {
    const int row = r - (4*D + 2*FFD);
    base = Woc + (size_t)l*D*FFD + (size_t)row*FFD; len = FFD;
    dst = (size_t)l*QL + 4ull*D*D + 2ull*FFD*D + (size_t)row*FFD;
  }
  const int nv = len >> 10;
  float4 rv[4];
  float sum = 0.f;
  #pragma unroll 4
  for (int i = 0; i < 4; ++i) {
    if (i < nv) {
      rv[i] = reinterpret_cast<const float4*>(base)[threadIdx.x + i*256];
      sum += fabsf(rv[i].x) + fabsf(rv[i].y) + fabsf(rv[i].z) + fabsf(rv[i].w);
    }
  }
  #pragma unroll
  for (int off = 32; off > 0; off >>= 1) sum += __shfl_down(sum, off);
  __shared__ float red[4]; __shared__ float sbc;
  if ((threadIdx.x & 63) == 0) red[threadIdx.x >> 6] = sum;
  __syncthreads();
  if (threadIdx.x == 0) {
    const float s = fmaxf((red[0]+red[1]+red[2]+red[3]) / (float)len, 1e-5f);
    sbc = s;
    scales[(size_t)l*ROWS_PER_LAYER + r] = s;
  }
  __syncthreads();
  const float hs = 0.5f * sbc;
  #pragma unroll 4
  for (int i = 0; i < 4; ++i) {
    if (i < nv) {
      const float4 v = rv[i];
      char4 q;
      q.x = v.x > hs ? 1 : (v.x < -hs ? -1 : 0);
      q.y = v.y > hs ? 1 : (v.y < -hs ? -1 : 0);
      q.z = v.z > hs ? 1 : (v.z < -hs ? -1 : 0);
      q.w = v.w > hs ? 1 : (v.w < -hs ? -1 : 0);
      reinterpret_cast<char4*>(qw + dst)[threadIdx.x + i*256] = q;
    }
  }
}

// ---------------------------------------------------------------------------
// Per-vocab-row i8 quantize of embed: s = max|row|/127; q = rint(w/s).
// ---------------------------------------------------------------------------
__global__ __launch_bounds__(256) void quant_embed_kernel(
    const float* __restrict__ embed, char* __restrict__ q, float* __restrict__ sw)
{
  const int row = blockIdx.x;
  const float4 v = reinterpret_cast<const float4*>(embed + (size_t)row*D)[threadIdx.x];
  float mx = fmaxf(fmaxf(fabsf(v.x), fabsf(v.y)), fmaxf(fabsf(v.z), fabsf(v.w)));
  #pragma unroll
  for (int off = 32; off > 0; off >>= 1) mx = fmaxf(mx, __shfl_down(mx, off));
  __shared__ float red[4]; __shared__ float sbc;
  if ((threadIdx.x & 63) == 0) red[threadIdx.x >> 6] = mx;
  __syncthreads();
  if (threadIdx.x == 0) {
    const float m = fmaxf(fmaxf(red[0], red[1]), fmaxf(red[2], red[3]));
    const float s = fmaxf(m, 1e-8f) * (1.f/127.f);
    sbc = 1.f / s;
    sw[row] = s;
  }
  __syncthreads();
  const float inv = sbc;
  char4 o;
  o.x = (char)__float2int_rn(v.x * inv); o.y = (char)__float2int_rn(v.y * inv);
  o.z = (char)__float2int_rn(v.z * inv); o.w = (char)__float2int_rn(v.w * inv);
  reinterpret_cast<char4*>(q + (size_t)row*D)[threadIdx.x] = o;
}

// ---------------------------------------------------------------------------
// h = rmsnorm(embed[idx], ln_in_w), f32 out. One block (256 thr) per row.
// ---------------------------------------------------------------------------
__global__ __launch_bounds__(256) void embed_rms_kernel(
    const int* __restrict__ idx, const float* __restrict__ embed,
    const float* __restrict__ g, float* __restrict__ h)
{
  const int row = blockIdx.x;
  const int tok = idx[row];
  const float4 xv = reinterpret_cast<const float4*>(embed + (size_t)tok*D)[threadIdx.x];
  float ss = xv.x*xv.x + xv.y*xv.y + xv.z*xv.z + xv.w*xv.w;
  #pragma unroll
  for (int off = 32; off > 0; off >>= 1) ss += __shfl_down(ss, off);
  __shared__ float red[4];
  if ((threadIdx.x & 63) == 0) red[threadIdx.x >> 6] = ss;
  __syncthreads();
  const float mean = (red[0]+red[1]+red[2]+red[3]) * (1.f/(float)D);
  const float rn = rsqrtf(mean + 1e-6f);
  const float4 gv = reinterpret_cast<const float4*>(g)[threadIdx.x];
  float4 ov;
  ov.x = xv.x*rn*gv.x; ov.y = xv.y*rn*gv.y; ov.z = xv.z*rn*gv.z; ov.w = xv.w*rn*gv.w;
  reinterpret_cast<float4*>(h + (size_t)row*D)[threadIdx.x] = ov;
}

// ---------------------------------------------------------------------------
// xn8 = i8-quantized rmsnorm(x, g) with per-row scale sx (fused, one pass).
// ---------------------------------------------------------------------------
__global__ __launch_bounds__(256) void rms_i8_kernel(
    const float* __restrict__ x, const float* __restrict__ g,
    char* __restrict__ q, float* __restrict__ sx)
{
  const int row = blockIdx.x;
  const float4 xv = reinterpret_cast<const float4*>(x + (size_t)row*D)[threadIdx.x];
  const float4 gv = reinterpret_cast<const float4*>(g)[threadIdx.x];
  float4 pv;
  pv.x = xv.x*gv.x; pv.y = xv.y*gv.y; pv.z = xv.z*gv.z; pv.w = xv.w*gv.w;
  float ss = xv.x*xv.x + xv.y*xv.y + xv.z*xv.z + xv.w*xv.w;
  float mg = fmaxf(fmaxf(fabsf(pv.x), fabsf(pv.y)), fmaxf(fabsf(pv.z), fabsf(pv.w)));
  #pragma unroll
  for (int off = 32; off > 0; off >>= 1) {
    ss += __shfl_down(ss, off);
    mg = fmaxf(mg, __shfl_down(mg, off));
  }
  __shared__ float reds[4], redm[4]; __shared__ float sbc;
  if ((threadIdx.x & 63) == 0) { reds[threadIdx.x >> 6] = ss; redm[threadIdx.x >> 6] = mg; }
  __syncthreads();
  if (threadIdx.x == 0) {
    const float mean = (reds[0]+reds[1]+reds[2]+reds[3]) * (1.f/(float)D);
    const float rn = rsqrtf(mean + 1e-6f);
    const float vmax = rn * fmaxf(fmaxf(redm[0], redm[1]), fmaxf(redm[2], redm[3]));
    const float s = fmaxf(vmax, 1e-8f) * (1.f/127.f);
    sx[row] = s;
    sbc = rn / s;
  }
  __syncthreads();
  const float f = sbc;
  char4 o;
  o.x = (char)__float2int_rn(pv.x * f); o.y = (char)__float2int_rn(pv.y * f);
  o.z = (char)__float2int_rn(pv.z * f); o.w = (char)__float2int_rn(pv.w * f);
  reinterpret_cast<char4*>(q + (size_t)row*D)[threadIdx.x] = o;
}

// ---------------------------------------------------------------------------
// Fused: h += p0 + p1; xn8 = i8 rmsnorm(h, g) + per-row scale sx.
// ---------------------------------------------------------------------------
__global__ __launch_bounds__(256) void rms_radd_i8_kernel(
    float* __restrict__ h, const float* __restrict__ p0,
    const float* __restrict__ p1, const float* __restrict__ g,
    char* __restrict__ q, float* __restrict__ sx)
{
  const int row = blockIdx.x;
  const size_t off = (size_t)row*D/4 + threadIdx.x;
  float4 hv = reinterpret_cast<const float4*>(h)[off];
  const float4 a = reinterpret_cast<const float4*>(p0)[off];
  const float4 b = reinterpret_cast<const float4*>(p1)[off];
  hv.x += a.x + b.x; hv.y += a.y + b.y; hv.z += a.z + b.z; hv.w += a.w + b.w;
  reinterpret_cast<float4*>(h)[off] = hv;
  const float4 gv = reinterpret_cast<const float4*>(g)[threadIdx.x];
  float4 pv;
  pv.x = hv.x*gv.x; pv.y = hv.y*gv.y; pv.z = hv.z*gv.z; pv.w = hv.w*gv.w;
  float ss = hv.x*hv.x + hv.y*hv.y + hv.z*hv.z + hv.w*hv.w;
  float mg = fmaxf(fmaxf(fabsf(pv.x), fabsf(pv.y)), fmaxf(fabsf(pv.z), fabsf(pv.w)));
  #pragma unroll
  for (int o2 = 32; o2 > 0; o2 >>= 1) {
    ss += __shfl_down(ss, o2);
    mg = fmaxf(mg, __shfl_down(mg, o2));
  }
  __shared__ float reds[4], redm[4]; __shared__ float sbc;
  if ((threadIdx.x & 63) == 0) { reds[threadIdx.x >> 6] = ss; redm[threadIdx.x >> 6] = mg; }
  __syncthreads();
  if (threadIdx.x == 0) {
    const float mean = (reds[0]+reds[1]+reds[2]+reds[3]) * (1.f/(float)D);
    const float rn = rsqrtf(mean + 1e-6f);
    const float vmax = rn * fmaxf(fmaxf(redm[0], redm[1]), fmaxf(redm[2], redm[3]));
    const float s = fmaxf(vmax, 1e-8f) * (1.f/127.f);
    sx[row] = s;
    sbc = rn / s;
  }
  __syncthreads();
  const float f = sbc;
  char4 o;
  o.x = (char)__float2int_rn(pv.x * f); o.y = (char)__float2int_rn(pv.y * f);
  o.z = (char)__float2int_rn(pv.z * f); o.w = (char)__float2int_rn(pv.w * f);
  reinterpret_cast<char4*>(q + (size_t)row*D)[threadIdx.x] = o;
}

// ---------------------------------------------------------------------------
// Per-row (len FFD=4096) i8 quantize of the FFN intermediate (f16 in).
// ---------------------------------------------------------------------------
__global__ __launch_bounds__(256) void quant_ffn_kernel(
    const f16* __restrict__ a, char* __restrict__ q, float* __restrict__ s)
{
  const int row = blockIdx.x;
  const size_t base = (size_t)row*(FFD/4);
  f16x4 v[4];
  float mx = 0.f;
  #pragma unroll
  for (int i = 0; i < 4; ++i) {
    v[i] = reinterpret_cast<const f16x4*>(a)[base + threadIdx.x + i*256];
    #pragma unroll
    for (int j = 0; j < 4; ++j) mx = fmaxf(mx, fabsf((float)v[i][j]));
  }
  #pragma unroll
  for (int off = 32; off > 0; off >>= 1) mx = fmaxf(mx, __shfl_down(mx, off));
  __shared__ float red[4]; __shared__ float sbc;
  if ((threadIdx.x & 63) == 0) red[threadIdx.x >> 6] = mx;
  __syncthreads();
  if (threadIdx.x == 0) {
    const float m = fmaxf(fmaxf(red[0], red[1]), fmaxf(red[2], red[3]));
    const float sr = fmaxf(m, 1e-8f) * (1.f/127.f);
    s[row] = sr;
    sbc = 1.f / sr;
  }
  __syncthreads();
  const float inv = sbc;
  #pragma unroll
  for (int i = 0; i < 4; ++i) {
    char4 o;
    o.x = (char)__float2int_rn((float)v[i][0] * inv);
    o.y = (char)__float2int_rn((float)v[i][1] * inv);
    o.z = (char)__float2int_rn((float)v[i][2] * inv);
    o.w = (char)__float2int_rn((float)v[i][3] * inv);
    reinterpret_cast<char4*>(q)[base + threadIdx.x + i*256] = o;
  }
}

// ---------------------------------------------------------------------------
// Time-mix recurrence: chunked prefix sum over T.
// ---------------------------------------------------------------------------
__global__ __launch_bounds__(256) void scan1_kernel(
    const float* __restrict__ k, const float* __restrict__ v, int ld,
    const float* __restrict__ decay, float* __restrict__ part)
{
  const int d = blockIdx.x*256 + threadIdx.x;
  const int c = blockIdx.y, b = blockIdx.z;
  const float dec = 1.f / (1.f + expf(-decay[d]));
  const float ldc = logf(fmaxf(dec, 1e-7f));
  float sum = 0.f;
  const int row0 = b*T + c*CT;
  #pragma unroll 4
  for (int t = 0; t < CT; ++t) {
    const size_t i = (size_t)(row0 + t)*ld + d;
    const float scale = expf((float)(c*CT + t) * ldc);
    sum += (k[i] * v[i]) / fmaxf(scale, 1e-10f);
  }
  part[((size_t)b*NT + c)*D + d] = sum;
}

__global__ __launch_bounds__(256) void scan23_kernel(
    const float* __restrict__ r, const float* __restrict__ k,
    const float* __restrict__ v, int ld, const float* __restrict__ decay,
    const float* __restrict__ part, float* __restrict__ rs)
{
  const int d = blockIdx.x*256 + threadIdx.x;
  const int c = blockIdx.y, b = blockIdx.z;
  const float dec = 1.f / (1.f + expf(-decay[d]));
  const float ldc = logf(fmaxf(dec, 1e-7f));
  float cum = 0.f;
  for (int j = 0; j < c; ++j) cum += part[((size_t)b*NT + j)*D + d];
  const int row0 = b*T + c*CT;
  #pragma unroll 4
  for (int t = 0; t < CT; ++t) {
    const size_t i = (size_t)(row0 + t)*ld + d;
    const float scale = expf((float)(c*CT + t) * ldc);
    cum += (k[i] * v[i]) / fmaxf(scale, 1e-10f);
    rs[(size_t)(row0 + t)*D + d] = r[i] * (cum * scale);
  }
}

// fallback-path kernels -------------------------------------------------------
__global__ __launch_bounds__(256) void rms_f16_kernel(
    const float* __restrict__ x, const float* __restrict__ g, f16* __restrict__ o)
{
  const int row = blockIdx.x;
  const float4 xv = reinterpret_cast<const float4*>(x + (size_t)row*D)[threadIdx.x];
  float ss = xv.x*xv.x + xv.y*xv.y + xv.z*xv.z + xv.w*xv.w;
  #pragma unroll
  for (int off = 32; off > 0; off >>= 1) ss += __shfl_down(ss, off);
  __shared__ float red[4];
  if ((threadIdx.x & 63) == 0) red[threadIdx.x >> 6] = ss;
  __syncthreads();
  const float mean = (red[0]+red[1]+red[2]+red[3]) * (1.f/(float)D);
  const float rn = rsqrtf(mean + 1e-6f);
  const float4 gv = reinterpret_cast<const float4*>(g)[threadIdx.x];
  f16x4 ov;
  ov[0] = (f16)(xv.x*rn*gv.x); ov[1] = (f16)(xv.y*rn*gv.y);
  ov[2] = (f16)(xv.z*rn*gv.z); ov[3] = (f16)(xv.w*rn*gv.w);
  reinterpret_cast<f16x4*>(o + (size_t)row*D)[threadIdx.x] = ov;
}

__global__ __launch_bounds__(256) void scan2_kernel(float* __restrict__ part)
{
  const int d = blockIdx.x*256 + threadIdx.x;
  const int b = blockIdx.y;
  float run = 0.f;
  #pragma unroll 8
  for (int c = 0; c < NT; ++c) {
    const size_t i = ((size_t)b*NT + c)*D + d;
    const float t = part[i];
    part[i] = run;
    run += t;
  }
}

__global__ __launch_bounds__(256) void scan3_kernel(
    const float* __restrict__ r, const float* __restrict__ k,
    const float* __restrict__ v, int ld, const float* __restrict__ decay,
    const float* __restrict__ part, float* __restrict__ rs)
{
  const int d = blockIdx.x*256 + threadIdx.x;
  const int c = blockIdx.y, b = blockIdx.z;
  const float dec = 1.f / (1.f + expf(-decay[d]));
  const float ldc = logf(fmaxf(dec, 1e-7f));
  float cum = part[((size_t)b*NT + c)*D + d];
  const int row0 = b*T + c*CT;
  #pragma unroll 4
  for (int t = 0; t < CT; ++t) {
    const size_t i = (size_t)(row0 + t)*ld + d;
    const float scale = expf((float)(c*CT + t) * ldc);
    cum += (k[i] * v[i]) / fmaxf(scale, 1e-10f);
    rs[(size_t)(row0 + t)*D + d] = r[i] * (cum * scale);
  }
}

__global__ __launch_bounds__(256) void silumul_kernel(
    const f16* __restrict__ a, const f16* __restrict__ b, f16* __restrict__ o, int n4)
{
  const int i = blockIdx.x*256 + threadIdx.x;
  if (i >= n4) return;
  const f16x4 av = reinterpret_cast<const f16x4*>(a)[i];
  const f16x4 bv = reinterpret_cast<const f16x4*>(b)[i];
  f16x4 ov;
  #pragma unroll
  for (int j = 0; j < 4; ++j) {
    const float x = (float)av[j];
    ov[j] = (f16)((x / (1.f + expf(-x))) * (float)bv[j]);
  }
  reinterpret_cast<f16x4*>(o)[i] = ov;
}

// ---------------------------------------------------------------------------
// XCD-chunked bijective block swizzle (m204).
// ---------------------------------------------------------------------------
__device__ __forceinline__ int xcd_swizzle(int fid, int nwg) {
  const int q = nwg >> 3, r = nwg & 7, x = fid & 7, o = fid >> 3;
  return (x < r ? x*(q+1) : r*(q+1) + (x-r)*q) + o;
}

// ---------------------------------------------------------------------------
// RING GEMM, INT8 (r11-proven): 3-buffer, depth-2 prefetch, counted vmcnt,
// ONE barrier/K-step. K-step 64, mfma_i32_16x16x64_i8.
// out[M,N] = epi( sx[row] * scl[col] * (A8 @ W8^T) ), f32 out. BN=128.
// EPI: 0 none, 2 +resid, 3 sigmoid iff col<D.
// SPLITK: gridDim.z pieces write outp + z*M*N.
// The <128,8,0> instantiation also serves as the HEAD (scl=sw, N=V):
// 48KB LDS -> 3 blocks/CU (vs the old 256-wide head's 72KB/2 blocks).
// ---------------------------------------------------------------------------
template<int BM, int NW, int EPI, bool SPLITK = false>
__global__ __launch_bounds__(NW*64) void gemm_i8_kernel(
    const char* __restrict__ A, const char* __restrict__ Bq,
    const float* __restrict__ sx, const float* __restrict__ scl,
    const float* __restrict__ resid, float* __restrict__ outp, int N, int K)
{
  constexpr int WN = 2;
  constexpr int WM = NW / WN;
  constexpr int MF = BM / (WM*16);
  constexpr int ACALLS = BM / (16*NW);
  constexpr int BCALLS = 128 / (16*NW);
  constexpr int VCNT = ACALLS + BCALLS;
  __shared__ __align__(16) char As[3][BM*64];
  __shared__ __align__(16) char Bs[3][128*64];

  const int tid = threadIdx.x;
  const int wave = tid >> 6, lane = tid & 63;
  const int gx = gridDim.x, nwg = gx * gridDim.y;
  const int wg = xcd_swizzle(blockIdx.x + blockIdx.y*gx, nwg);
  const int m0 = (wg % gx) * BM, n0 = (wg / gx) * 128;
  const int lr = lane & 15, kg = lane >> 4;
  const int wm0 = (wave / WN) * (MF*16), wn0 = (wave % WN) * 64;
  const int grow = lane >> 2;
  const int gcol = (lane & 3) * 16;
  const char* Ab = A  + (size_t)(m0 + grow)*K + gcol;
  const char* Bb = Bq + (size_t)(n0 + grow)*K + gcol;

  int kbeg = 0, kend = K;
  size_t obase = 0;
  if (SPLITK) {
    const int kc = K / gridDim.z;
    kbeg = blockIdx.z * kc; kend = kbeg + kc;
    obase = (size_t)blockIdx.z * M * (size_t)N;
  }
  const int NKT = (kend - kbeg) / 64;

  auto stage = [&](int buf, int k0) {
    #pragma unroll
    for (int c = 0; c < ACALLS; ++c) {
      const int rb = (c*NW + wave) * 16;
      gload16b(Ab + (size_t)rb*K + k0, &As[buf][rb*64]);
    }
    #pragma unroll
    for (int c = 0; c < BCALLS; ++c) {
      const int rb = (c*NW + wave) * 16;
      gload16b(Bb + (size_t)rb*K + k0, &Bs[buf][rb*64]);
    }
  };

  i32x4 acc[MF][4] = {};
  stage(0, kbeg);
  stage(1, kbeg + 64);

  int cur = 0;
  for (int t = 0; t < NKT; ++t) {
    vm_wait<VCNT>();
    ring_barrier();
    if (t + 2 < NKT) {
      int nb = cur + 2; if (nb >= 3) nb -= 3;
      stage(nb, kbeg + (t + 2) * 64);
    }
    i32x4 af[MF], bf[4];
    #pragma unroll
    for (int i = 0; i < MF; ++i)
      af[i] = *reinterpret_cast<const i32x4*>(&As[cur][(wm0 + i*16 + lr)*64 + kg*16]);
    #pragma unroll
    for (int j = 0; j < 4; ++j)
      bf[j] = *reinterpret_cast<const i32x4*>(&Bs[cur][(wn0 + j*16 + lr)*64 + kg*16]);
    #pragma unroll
    for (int i = 0; i < MF; ++i)
      #pragma unroll
      for (int j = 0; j < 4; ++j)
        acc[i][j] = __builtin_amdgcn_mfma_i32_16x16x64_i8(af[i], bf[j], acc[i][j], 0, 0, 0);
    ++cur; if (cur == 3) cur = 0;
  }

  // C/D frag layout: col=lane&15, row=(lane>>4)*4+e (dtype-independent)
  #pragma unroll
  for (int j = 0; j < 4; ++j) {
    const int col = n0 + wn0 + j*16 + lr;
    const float sv = scl[col];
    #pragma unroll
    for (int i = 0; i < MF; ++i) {
      #pragma unroll
      for (int e = 0; e < 4; ++e) {
        const int row = m0 + wm0 + i*16 + kg*4 + e;
        float y = (float)acc[i][j][e] * sx[row] * sv;
        if (EPI == 3 && col < D) y = 1.f / (1.f + expf(-y));
        if (EPI == 2) y += resid[(size_t)row*N + col];
        outp[obase + (size_t)row*N + col] = y;
      }
    }
  }
}

// ---------------------------------------------------------------------------
// RING FUSED FFN GEMM, INT8 (r11-proven): g16 = (f16)( silu(.)*(.) ).
// 128x128 tile, 8 waves, ring-3, K-step 64.
// ---------------------------------------------------------------------------
__global__ __launch_bounds__(512) void gemm_ffn_i8_kernel(
    const char* __restrict__ A, const char* __restrict__ B1, const char* __restrict__ B2,
    const float* __restrict__ sx, const float* __restrict__ s1, const float* __restrict__ s2,
    f16* __restrict__ outg, int N, int K)
{
  constexpr int BM = 128, BN = 128;
  __shared__ __align__(16) char As [3][BM*64];
  __shared__ __align__(16) char B1s[3][BN*64];
  __shared__ __align__(16) char B2s[3][BN*64];
  const int tid = threadIdx.x;
  const int wave = tid >> 6, lane = tid & 63;
  const int gx = gridDim.x, nwg = gx * gridDim.y;
  const int wg = xcd_swizzle(blockIdx.x + blockIdx.y*gx, nwg);
  const int m0 = (wg % gx) * BM, n0 = (wg / gx) * BN;
  const int lr = lane & 15, kg = lane >> 4;
  const int wm0 = (wave >> 1) * 32, wn0 = (wave & 1) * 64;  // 8 waves: 4M x 2N
  const int grow = lane >> 2;
  const int gcol = (lane & 3) * 16;
  const char* Ab  = A  + (size_t)(m0 + grow)*K + gcol;
  const char* B1b = B1 + (size_t)(n0 + grow)*K + gcol;
  const char* B2b = B2 + (size_t)(n0 + grow)*K + gcol;

  auto stage = [&](int buf, int k0) {
    const int rb = wave * 16;
    gload16b(Ab  + (size_t)rb*K + k0, &As [buf][rb*64]);
    gload16b(B1b + (size_t)rb*K + k0, &B1s[buf][rb*64]);
    gload16b(B2b + (size_t)rb*K + k0, &B2s[buf][rb*64]);
  };

  i32x4 aca[2][4] = {};
  i32x4 acb[2][4] = {};
  stage(0, 0);
  stage(1, 64);

  const int NKT = K / 64;
  int cur = 0;
  for (int t = 0; t < NKT; ++t) {
    vm_wait<3>();
    ring_barrier();
    if (t + 2 < NKT) {
      int nb = cur + 2; if (nb >= 3) nb -= 3;
      stage(nb, (t + 2) * 64);
    }
    i32x4 af[2], b1f[4], b2f[4];
    #pragma unroll
    for (int i = 0; i < 2; ++i)
      af[i] = *reinterpret_cast<const i32x4*>(&As[cur][(wm0 + i*16 + lr)*64 + kg*16]);
    #pragma unroll
    for (int j = 0; j < 4; ++j) {
      b1f[j] = *reinterpret_cast<const i32x4*>(&B1s[cur][(wn0 + j*16 + lr)*64 + kg*16]);
      b2f[j] = *reinterpret_cast<const i32x4*>(&B2s[cur][(wn0 + j*16 + lr)*64 + kg*16]);
    }
    #pragma unroll
    for (int i = 0; i < 2; ++i)
      #pragma unroll
      for (int j = 0; j < 4; ++j) {
        aca[i][j] = __builtin_amdgcn_mfma_i32_16x16x64_i8(af[i], b1f[j], aca[i][j], 0, 0, 0);
        acb[i][j] = __builtin_amdgcn_mfma_i32_16x16x64_i8(af[i], b2f[j], acb[i][j], 0, 0, 0);
      }
    ++cur; if (cur == 3) cur = 0;
  }
  #pragma unroll
  for (int j = 0; j < 4; ++j) {
    const int col = n0 + wn0 + j*16 + lr;
    const float sa = s1[col], sb = s2[col];
    #pragma unroll
    for (int i = 0; i < 2; ++i) {
      #pragma unroll
      for (int e = 0; e < 4; ++e) {
        const int row = m0 + wm0 + i*16 + kg*4 + e;
        const float srow = sx[row];
        const float a = (float)aca[i][j][e] * srow * sa;
        const float b = (float)acb[i][j][e] * srow * sb;
        outg[(size_t)row*N + col] = (f16)((a / (1.f + expf(-a))) * b);
      }
    }
  }
}

// ---------------------------------------------------------------------------
// FALLBACK GEMM: inline quantize from f32 weights (used if ws too small).
// ---------------------------------------------------------------------------
__global__ __launch_bounds__(64) void scales_kernel(
    const float* __restrict__ Wr, const float* __restrict__ Wk,
    const float* __restrict__ Wv, const float* __restrict__ Wo,
    const float* __restrict__ W1, const float* __restrict__ W2,
    const float* __restrict__ Woc, float* __restrict__ s)
{
  const int r = blockIdx.x, l = blockIdx.y;
  const float* base; int len;
  if (r < 4*D) {
    const int m = r >> 10, row = r & (D-1);
    const float* Wm = (m==0) ? Wr : (m==1) ? Wk : (m==2) ? Wv : Wo;
    base = Wm + (size_t)l*D*D + (size_t)row*D; len = D;
  } else if (r < 4*D + 2*FFD) {
    int row = r - 4*D;
    const float* Wm = (row < FFD) ? W1 : W2;
    if (row >= FFD) row -= FFD;
    base = Wm + (size_t)l*FFD*D + (size_t)row*D; len = D;
  } else {
    const int row = r - (4*D + 2*FFD);
    base = Woc + (size_t)l*D*FFD + (size_t)row*FFD; len = FFD;
  }
  float sum = 0.f;
  for (int i = threadIdx.x; i < len; i += 64) sum += fabsf(base[i]);
  #pragma unroll
  for (int off = 32; off > 0; off >>= 1) sum += __shfl_down(sum, off);
  if (threadIdx.x == 0)
    s[(size_t)l*ROWS_PER_LAYER + r] = fmaxf(sum / (float)len, 1e-5f);
}

template<int BM, int EPI, bool QUANT, bool OUTF16>
__global__ __launch_bounds__(256) void gemm_bt_kernel(
    const f16* __restrict__ A, const float* __restrict__ Bw,
    const float* __restrict__ scl, const float* __restrict__ resid,
    void* __restrict__ outp, int N, int K)
{
  constexpr int BN = 128, LDT = 40;
  constexpr int MF = (BM == 128) ? 4 : 2;
  __shared__ f16 As[BM*LDT];
  __shared__ f16 Bs[BN*LDT];
  const int tid = threadIdx.x;
  const int m0 = blockIdx.y * BM, n0 = blockIdx.x * BN;
  const int wave = tid >> 6, lane = tid & 63;
  const int lr = lane & 15, kg = lane >> 4;
  const int wm0 = (wave >> 1) * (MF*16), wn0 = (wave & 1) * 64;
  f32x4 acc[MF][4] = {};
  for (int k0 = 0; k0 < K; k0 += 32) {
    #pragma unroll
    for (int c = 0; c < (BM*4)/256; ++c) {
      const int chunk = tid + c*256;
      const int row = chunk >> 2, c8 = (chunk & 3) << 3;
      *reinterpret_cast<f16x8*>(&As[row*LDT + c8]) =
        *reinterpret_cast<const f16x8*>(A + (size_t)(m0+row)*K + k0 + c8);
    }
    #pragma unroll
    for (int c = 0; c < 2; ++c) {
      const int chunk = tid + c*256;
      const int row = chunk >> 2, c8 = (chunk & 3) << 3;
      const float* bp = Bw + (size_t)(n0+row)*K + k0 + c8;
      const float4 f0 = *reinterpret_cast<const float4*>(bp);
      const float4 f1 = *reinterpret_cast<const float4*>(bp + 4);
      const float wv[8] = {f0.x,f0.y,f0.z,f0.w,f1.x,f1.y,f1.z,f1.w};
      f16x8 qv;
      if (QUANT) {
        const float hs = 0.5f * scl[n0+row];
        #pragma unroll
        for (int j = 0; j < 8; ++j)
          qv[j] = wv[j] > hs ? (f16)1.f : (wv[j] < -hs ? (f16)(-1.f) : (f16)0.f);
      } else {
        #pragma unroll
        for (int j = 0; j < 8; ++j) qv[j] = (f16)wv[j];
      }
      *reinterpret_cast<f16x8*>(&Bs[row*LDT + c8]) = qv;
    }
    __syncthreads();
    f16x8 af[MF], bf[4];
    #pragma unroll
    for (int i = 0; i < MF; ++i)
      af[i] = *reinterpret_cast<const f16x8*>(&As[(wm0 + i*16 + lr)*LDT + kg*8]);
    #pragma unroll
    for (int j = 0; j < 4; ++j)
      bf[j] = *reinterpret_cast<const f16x8*>(&Bs[(wn0 + j*16 + lr)*LDT + kg*8]);
    #pragma unroll
    for (int i = 0; i < MF; ++i)
      #pragma unroll
      for (int j = 0; j < 4; ++j)
        acc[i][j] = __builtin_amdgcn_mfma_f32_16x16x32_f16(af[i], bf[j], acc[i][j], 0, 0, 0);
    __syncthreads();
  }
  #pragma unroll
  for (int j = 0; j < 4; ++j) {
    const int col = n0 + wn0 + j*16 + lr;
    const float sv = QUANT ? scl[col] : 1.f;
    #pragma unroll
    for (int i = 0; i < MF; ++i) {
      #pragma unroll
      for (int e = 0; e < 4; ++e) {
        const int row = m0 + wm0 + i*16 + kg*4 + e;
        float y = acc[i][j][e] * sv;
        if (EPI == 1) y = 1.f / (1.f + expf(-y));
        if (EPI == 2) y += resid[(size_t)row*N + col];
        if (OUTF16) reinterpret_cast<f16*>(outp)[(size_t)row*N + col] = (f16)y;
        else        reinterpret_cast<float*>(outp)[(size_t)row*N + col] = y;
      }
    }
  }
}

// ---------------------------------------------------------------------------
extern "C" void kernel_launch(void* const* d_in, const int* in_sizes, int n_in,
                              void* d_out, int out_size, void* d_ws, size_t ws_size,
                              hipStream_t stream)
{
  (void)in_sizes; (void)n_in; (void)out_size;
  const int*   idx      = (const int*)  d_in[0];
  const float* embed    = (const float*)d_in[1];
  const float* ln_in_w  = (const float*)d_in[2];
  const float* ln1_w    = (const float*)d_in[3];
  const float* Wr       = (const float*)d_in[4];
  const float* Wk       = (const float*)d_in[5];
  const float* Wv       = (const float*)d_in[6];
  const float* Wo_t     = (const float*)d_in[7];
  const float* decay    = (const float*)d_in[8];
  const float* lnx_w    = (const float*)d_in[9];
  const float* ln2_w    = (const float*)d_in[10];
  const float* W1       = (const float*)d_in[11];
  const float* W2       = (const float*)d_in[12];
  const float* Wo_c     = (const float*)d_in[13];
  const float* ln_out_w = (const float*)d_in[14];
  float* out = (float*)d_out;

  char* p = (char*)d_ws;
  auto alloc = [&](size_t bytes) { void* q = (void*)p; p += (bytes + 255) & ~(size_t)255; return q; };
  float* h      = (float*)alloc((size_t)M*D*sizeof(float));
  f16*   xn     = (f16*)  alloc((size_t)M*D*sizeof(f16));       // fallback only
  float* rkv    = (float*)alloc((size_t)M*RKV*sizeof(float));   // r|k|v; reused as split-K partials
  float* rsb    = (float*)alloc((size_t)M*D*sizeof(float));
  f16*   abf    = (f16*)  alloc((size_t)M*FFD*sizeof(f16));
  f16*   bbf    = (f16*)  alloc((size_t)M*FFD*sizeof(f16));     // fallback only
  float* scales = (float*)alloc((size_t)NL*ROWS_PER_LAYER*sizeof(float));
  float* part   = (float*)alloc((size_t)BB*NT*D*sizeof(float));
  const size_t base_need = (size_t)(p - (char*)d_ws);
  const size_t fast_need = base_need + (NL*QL + 256)
      + ((size_t)V*D + 256) + (V*sizeof(float) + 256)
      + ((size_t)M*D + 256) + (M*sizeof(float) + 256)
      + ((size_t)M*FFD + 256) + (M*sizeof(float) + 256);

  embed_rms_kernel<<<M, 256, 0, stream>>>(idx, embed, ln_in_w, h);

  const dim3 gS(D/256, NT, BB);   // scan1/scan23: 512 blocks
  const dim3 gS2(D/256, BB);      // scan2 (fallback): 8 blocks

  if (ws_size >= fast_need) {
    // ================= FAST PATH: i8 weights + i8 activations =================
    char*  qw8  = (char*) alloc(NL*QL);
    char*  emb8 = (char*) alloc((size_t)V*D);
    float* sw   = (float*)alloc((size_t)V*sizeof(float));
    char*  xn8  = (char*) alloc((size_t)M*D);
    float* sx   = (float*)alloc((size_t)M*sizeof(float));
    char*  abf8 = (char*) alloc((size_t)M*FFD);
    float* sax  = (float*)alloc((size_t)M*sizeof(float));
    quant_kernel<<<dim3(ROWS_PER_LAYER, NL), 256, 0, stream>>>(Wr, Wk, Wv, Wo_t, W1, W2, Wo_c, qw8, scales);
    quant_embed_kernel<<<V, 256, 0, stream>>>(embed, emb8, sw);

    const dim3 gRKV(M/128, RKV/128);     // 16 x 24 = 384 blocks, 8 waves
    const dim3 gO(M/64, D/128);          // 32 x 8  = 256 blocks, 4 waves
    const dim3 gOC(M/64, D/128, 2);      // 512 blocks (split-K x2)
    const dim3 gFFN(M/128, FFD/128);     // 16 x 32 = 512 blocks, 8 waves
    const dim3 gHEAD(M/128, V/128);      // 16 x 250 = 4000 blocks, 8 waves, 48KB LDS

    rms_i8_kernel<<<M, 256, 0, stream>>>(h, ln1_w, xn8, sx);   // first layer's ln1
    for (int l = 0; l < NL; ++l) {
      const float* sl = scales + (size_t)l*ROWS_PER_LAYER;
      const char* qb = qw8 + (size_t)l*QL;
      const char *qrkv = qb, *qo = qb + 3ull*D*D;
      const char *q1 = qb + 4ull*D*D, *q2 = qb + 4ull*D*D + (size_t)FFD*D;
      const char *qoc = qb + 4ull*D*D + 2ull*(size_t)FFD*D;
      const float* dcy = decay + (size_t)l*D;
      // ---- time mix ----
      gemm_i8_kernel<128,8,3><<<gRKV, 512, 0, stream>>>(xn8, qrkv, sx, sl, nullptr, rkv, RKV, D);
      scan1_kernel<<<gS, 256, 0, stream>>>(rkv + D, rkv + 2*D, RKV, dcy, part);
      scan23_kernel<<<gS, 256, 0, stream>>>(rkv, rkv + D, rkv + 2*D, RKV, dcy, part, rsb);
      rms_i8_kernel<<<M, 256, 0, stream>>>(rsb, lnx_w + (size_t)l*D, xn8, sx);
      gemm_i8_kernel<64,4,2><<<gO, 256, 0, stream>>>(xn8, qo, sx, sl + 3*D, h, h, D, D);
      // ---- channel mix ----
      rms_i8_kernel<<<M, 256, 0, stream>>>(h, ln2_w + (size_t)l*D, xn8, sx);
      gemm_ffn_i8_kernel<<<gFFN, 512, 0, stream>>>(xn8, q1, q2, sx, sl + 4*D, sl + 4*D + FFD, abf, FFD, D);
      quant_ffn_kernel<<<M, 256, 0, stream>>>(abf, abf8, sax);
      gemm_i8_kernel<64,4,0,true><<<gOC, 256, 0, stream>>>(abf8, qoc, sax, sl + 4*D + 2*FFD, nullptr, rkv, D, FFD);
      const float* gnext = (l + 1 < NL) ? (ln1_w + (size_t)(l+1)*D) : ln_out_w;
      rms_radd_i8_kernel<<<M, 256, 0, stream>>>(h, rkv, rkv + (size_t)M*D, gnext, xn8, sx);
    }
    // ---- weight-tied head: reuse the proven 128x128 8-wave i8 ring
    // (48KB LDS -> 3 blocks/CU; epilogue out = acc*sx[row]*sw[col]) ----
    gemm_i8_kernel<128,8,0><<<gHEAD, 512, 0, stream>>>(xn8, emb8, sx, sw, nullptr, out, V, D);
  } else {
    // ================= FALLBACK: inline-quant f16 path =================
    float* rbuf = rkv;
    float* kbuf = rkv + (size_t)M*D;
    float* vbuf = rkv + 2ull*M*D;
    scales_kernel<<<dim3(ROWS_PER_LAYER, NL), 64, 0, stream>>>(Wr, Wk, Wv, Wo_t, W1, W2, Wo_c, scales);
    const dim3 gD(D/128, M/64);
    const dim3 gF(FFD/128, M/128);
    for (int l = 0; l < NL; ++l) {
      const float* sl = scales + (size_t)l*ROWS_PER_LAYER;
      const float* dcy = decay + (size_t)l*D;
      rms_f16_kernel<<<M, 256, 0, stream>>>(h, ln1_w + (size_t)l*D, xn);
      gemm_bt_kernel<64,1,true,false><<<gD, 256, 0, stream>>>(xn, Wr + (size_t)l*D*D, sl,       nullptr, rbuf, D, D);
      gemm_bt_kernel<64,0,true,false><<<gD, 256, 0, stream>>>(xn, Wk + (size_t)l*D*D, sl + D,   nullptr, kbuf, D, D);
      gemm_bt_kernel<64,0,true,false><<<gD, 256, 0, stream>>>(xn, Wv + (size_t)l*D*D, sl + 2*D, nullptr, vbuf, D, D);
      scan1_kernel<<<gS, 256, 0, stream>>>(kbuf, vbuf, D, dcy, part);
      scan2_kernel<<<gS2, 256, 0, stream>>>(part);
      scan3_kernel<<<gS, 256, 0, stream>>>(rbuf, kbuf, vbuf, D, dcy, part, rsb);
      rms_f16_kernel<<<M, 256, 0, stream>>>(rsb, lnx_w + (size_t)l*D, xn);
      gemm_bt_kernel<64,2,true,false><<<gD, 256, 0, stream>>>(xn, Wo_t + (size_t)l*D*D, sl + 3*D, h, h, D, D);
      rms_f16_kernel<<<M, 256, 0, stream>>>(h, ln2_w + (size_t)l*D, xn);
      gemm_bt_kernel<128,0,true,true><<<gF, 256, 0, stream>>>(xn, W1 + (size_t)l*FFD*D, sl + 4*D,       nullptr, abf, FFD, D);
      gemm_bt_kernel<128,0,true,true><<<gF, 256, 0, stream>>>(xn, W2 + (size_t)l*FFD*D, sl + 4*D + FFD, nullptr, bbf, FFD, D);
      silumul_kernel<<<(M*FFD/4)/256, 256, 0, stream>>>(abf, bbf, abf, M*FFD/4);
      gemm_bt_kernel<64,2,true,false><<<gD, 256, 0, stream>>>(abf, Wo_c + (size_t)l*D*FFD, sl + 4*D + 2*FFD, h, h, D, FFD);
    }
    rms_f16_kernel<<<M, 256, 0, stream>>>(h, ln_out_w, xn);
    gemm_bt_kernel<128,0,false,false><<<dim3(V/128, M/128), 256, 0, stream>>>(xn, embed, nullptr, nullptr, out, V, D);
  }
}

// Round 15
// 1124.774 us; speedup vs baseline: 1.0858x; 1.0064x over previous
//
#include <hip/hip_runtime.h>

typedef _Float16 f16;
typedef _Float16 f16x8 __attribute__((ext_vector_type(8)));
typedef _Float16 f16x4 __attribute__((ext_vector_type(4)));
typedef float f32x4 __attribute__((ext_vector_type(4)));
typedef int i32x4 __attribute__((ext_vector_type(4)));

static constexpr int BB = 2, T = 1024, D = 1024, FFD = 4096, V = 32000, NL = 6;
static constexpr int M = BB * T;                       // 2048 rows
static constexpr int ROWS_PER_LAYER = 4*D + 2*FFD + D; // 13312 scale rows per layer
static constexpr size_t QL = 4ull*D*D + 2ull*FFD*D + (size_t)D*FFD; // 16.78M elems/layer
static constexpr int NT = 64, CT = T / NT;             // scan: 64 chunks x 16 steps
static constexpr int RKV = 3*D;                        // fused rkv row stride

// direct global->LDS, 16B per lane. lds base wave-uniform; HW writes lane i at
// lds + i*16 (m104).
__device__ __forceinline__ void gload16b(const void* g, void* l) {
  __builtin_amdgcn_global_load_lds(
      (const __attribute__((address_space(1))) void*)g,
      (__attribute__((address_space(3))) void*)l, 16, 0, 0);
}
// counted vmcnt wait: allow the newest stage's N loads to remain in flight.
template<int N> __device__ __forceinline__ void vm_wait() {
  static_assert(N >= 2 && N <= 4, "unsupported vmcnt");
  if constexpr (N == 2) asm volatile("s_waitcnt vmcnt(2)" ::: "memory");
  else if constexpr (N == 3) asm volatile("s_waitcnt vmcnt(3)" ::: "memory");
  else                       asm volatile("s_waitcnt vmcnt(4)" ::: "memory");
}
// ring-phase boundary: all waves' reads of the oldest buffer are complete;
// sched_barrier pins the next stage AFTER the barrier.
__device__ __forceinline__ void ring_barrier() {
  __builtin_amdgcn_s_barrier();
  __builtin_amdgcn_sched_barrier(0);
}

// ---------------------------------------------------------------------------
// Single-pass per-row scale + ternary-quantize to i8 (EXACT: w_q in {-1,0,1}).
// qw layout per layer: [qr(D,D) qk qv qo | q1(FFD,D) q2 | qoc(D,FFD)]
// ---------------------------------------------------------------------------
__global__ __launch_bounds__(256) void quant_kernel(
    const float* __restrict__ Wr, const float* __restrict__ Wk,
    const float* __restrict__ Wv, const float* __restrict__ Wo,
    const float* __restrict__ W1, const float* __restrict__ W2,
    const float* __restrict__ Woc, char* __restrict__ qw, float* __restrict__ scales)
{
  const int r = blockIdx.x, l = blockIdx.y;
  const float* base; int len; size_t dst;
  if (r < 4*D) {
    const int m = r >> 10, row = r & (D-1);
    const float* Wm = (m==0) ? Wr : (m==1) ? Wk : (m==2) ? Wv : Wo;
    base = Wm + (size_t)l*D*D + (size_t)row*D; len = D;
    dst = (size_t)l*QL + (size_t)m*D*D + (size_t)row*D;
  } else if (r < 4*D + 2*FFD) {
    int row = r - 4*D;
    const int m = row >= FFD; if (m) row -= FFD;
    const float* Wm = m ? W2 : W1;
    base = Wm + (size_t)l*FFD*D + (size_t)row*D; len = D;
    dst = (size_t)l*QL + 4ull*D*D + (size_t)m*FFD*D + (size_t)row*D;
  } else {
    const int row = r - (4*D + 2*FFD);
    base = Woc + (size_t)l*D*FFD + (size_t)row*FFD; len = FFD;
    dst = (size_t)l*QL + 4ull*D*D + 2ull*FFD*D + (size_t)row*FFD;
  }
  const int nv = len >> 10;
  float4 rv[4];
  float sum = 0.f;
  #pragma unroll 4
  for (int i = 0; i < 4; ++i) {
    if (i < nv) {
      rv[i] = reinterpret_cast<const float4*>(base)[threadIdx.x + i*256];
      sum += fabsf(rv[i].x) + fabsf(rv[i].y) + fabsf(rv[i].z) + fabsf(rv[i].w);
    }
  }
  #pragma unroll
  for (int off = 32; off > 0; off >>= 1) sum += __shfl_down(sum, off);
  __shared__ float red[4]; __shared__ float sbc;
  if ((threadIdx.x & 63) == 0) red[threadIdx.x >> 6] = sum;
  __syncthreads();
  if (threadIdx.x == 0) {
    const float s = fmaxf((red[0]+red[1]+red[2]+red[3]) / (float)len, 1e-5f);
    sbc = s;
    scales[(size_t)l*ROWS_PER_LAYER + r] = s;
  }
  __syncthreads();
  const float hs = 0.5f * sbc;
  #pragma unroll 4
  for (int i = 0; i < 4; ++i) {
    if (i < nv) {
      const float4 v = rv[i];
      char4 q;
      q.x = v.x > hs ? 1 : (v.x < -hs ? -1 : 0);
      q.y = v.y > hs ? 1 : (v.y < -hs ? -1 : 0);
      q.z = v.z > hs ? 1 : (v.z < -hs ? -1 : 0);
      q.w = v.w > hs ? 1 : (v.w < -hs ? -1 : 0);
      reinterpret_cast<char4*>(qw + dst)[threadIdx.x + i*256] = q;
    }
  }
}

// ---------------------------------------------------------------------------
// Per-vocab-row i8 quantize of embed: s = max|row|/127; q = rint(w/s).
// ---------------------------------------------------------------------------
__global__ __launch_bounds__(256) void quant_embed_kernel(
    const float* __restrict__ embed, char* __restrict__ q, float* __restrict__ sw)
{
  const int row = blockIdx.x;
  const float4 v = reinterpret_cast<const float4*>(embed + (size_t)row*D)[threadIdx.x];
  float mx = fmaxf(fmaxf(fabsf(v.x), fabsf(v.y)), fmaxf(fabsf(v.z), fabsf(v.w)));
  #pragma unroll
  for (int off = 32; off > 0; off >>= 1) mx = fmaxf(mx, __shfl_down(mx, off));
  __shared__ float red[4]; __shared__ float sbc;
  if ((threadIdx.x & 63) == 0) red[threadIdx.x >> 6] = mx;
  __syncthreads();
  if (threadIdx.x == 0) {
    const float m = fmaxf(fmaxf(red[0], red[1]), fmaxf(red[2], red[3]));
    const float s = fmaxf(m, 1e-8f) * (1.f/127.f);
    sbc = 1.f / s;
    sw[row] = s;
  }
  __syncthreads();
  const float inv = sbc;
  char4 o;
  o.x = (char)__float2int_rn(v.x * inv); o.y = (char)__float2int_rn(v.y * inv);
  o.z = (char)__float2int_rn(v.z * inv); o.w = (char)__float2int_rn(v.w * inv);
  reinterpret_cast<char4*>(q + (size_t)row*D)[threadIdx.x] = o;
}

// ---------------------------------------------------------------------------
// h = rmsnorm(embed[idx], ln_in_w), f32 out. One block (256 thr) per row.
// ---------------------------------------------------------------------------
__global__ __launch_bounds__(256) void embed_rms_kernel(
    const int* __restrict__ idx, const float* __restrict__ embed,
    const float* __restrict__ g, float* __restrict__ h)
{
  const int row = blockIdx.x;
  const int tok = idx[row];
  const float4 xv = reinterpret_cast<const float4*>(embed + (size_t)tok*D)[threadIdx.x];
  float ss = xv.x*xv.x + xv.y*xv.y + xv.z*xv.z + xv.w*xv.w;
  #pragma unroll
  for (int off = 32; off > 0; off >>= 1) ss += __shfl_down(ss, off);
  __shared__ float red[4];
  if ((threadIdx.x & 63) == 0) red[threadIdx.x >> 6] = ss;
  __syncthreads();
  const float mean = (red[0]+red[1]+red[2]+red[3]) * (1.f/(float)D);
  const float rn = rsqrtf(mean + 1e-6f);
  const float4 gv = reinterpret_cast<const float4*>(g)[threadIdx.x];
  float4 ov;
  ov.x = xv.x*rn*gv.x; ov.y = xv.y*rn*gv.y; ov.z = xv.z*rn*gv.z; ov.w = xv.w*rn*gv.w;
  reinterpret_cast<float4*>(h + (size_t)row*D)[threadIdx.x] = ov;
}

// ---------------------------------------------------------------------------
// xn8 = i8-quantized rmsnorm(x, g) with per-row scale sx (fused, one pass).
// ---------------------------------------------------------------------------
__global__ __launch_bounds__(256) void rms_i8_kernel(
    const float* __restrict__ x, const float* __restrict__ g,
    char* __restrict__ q, float* __restrict__ sx)
{
  const int row = blockIdx.x;
  const float4 xv = reinterpret_cast<const float4*>(x + (size_t)row*D)[threadIdx.x];
  const float4 gv = reinterpret_cast<const float4*>(g)[threadIdx.x];
  float4 pv;
  pv.x = xv.x*gv.x; pv.y = xv.y*gv.y; pv.z = xv.z*gv.z; pv.w = xv.w*gv.w;
  float ss = xv.x*xv.x + xv.y*xv.y + xv.z*xv.z + xv.w*xv.w;
  float mg = fmaxf(fmaxf(fabsf(pv.x), fabsf(pv.y)), fmaxf(fabsf(pv.z), fabsf(pv.w)));
  #pragma unroll
  for (int off = 32; off > 0; off >>= 1) {
    ss += __shfl_down(ss, off);
    mg = fmaxf(mg, __shfl_down(mg, off));
  }
  __shared__ float reds[4], redm[4]; __shared__ float sbc;
  if ((threadIdx.x & 63) == 0) { reds[threadIdx.x >> 6] = ss; redm[threadIdx.x >> 6] = mg; }
  __syncthreads();
  if (threadIdx.x == 0) {
    const float mean = (reds[0]+reds[1]+reds[2]+reds[3]) * (1.f/(float)D);
    const float rn = rsqrtf(mean + 1e-6f);
    const float vmax = rn * fmaxf(fmaxf(redm[0], redm[1]), fmaxf(redm[2], redm[3]));
    const float s = fmaxf(vmax, 1e-8f) * (1.f/127.f);
    sx[row] = s;
    sbc = rn / s;
  }
  __syncthreads();
  const float f = sbc;
  char4 o;
  o.x = (char)__float2int_rn(pv.x * f); o.y = (char)__float2int_rn(pv.y * f);
  o.z = (char)__float2int_rn(pv.z * f); o.w = (char)__float2int_rn(pv.w * f);
  reinterpret_cast<char4*>(q + (size_t)row*D)[threadIdx.x] = o;
}

// ---------------------------------------------------------------------------
// Fused: h += p0 + p1; xn8 = i8 rmsnorm(h, g) + per-row scale sx.
// ---------------------------------------------------------------------------
__global__ __launch_bounds__(256) void rms_radd_i8_kernel(
    float* __restrict__ h, const float* __restrict__ p0,
    const float* __restrict__ p1, const float* __restrict__ g,
    char* __restrict__ q, float* __restrict__ sx)
{
  const int row = blockIdx.x;
  const size_t off = (size_t)row*D/4 + threadIdx.x;
  float4 hv = reinterpret_cast<const float4*>(h)[off];
  const float4 a = reinterpret_cast<const float4*>(p0)[off];
  const float4 b = reinterpret_cast<const float4*>(p1)[off];
  hv.x += a.x + b.x; hv.y += a.y + b.y; hv.z += a.z + b.z; hv.w += a.w + b.w;
  reinterpret_cast<float4*>(h)[off] = hv;
  const float4 gv = reinterpret_cast<const float4*>(g)[threadIdx.x];
  float4 pv;
  pv.x = hv.x*gv.x; pv.y = hv.y*gv.y; pv.z = hv.z*gv.z; pv.w = hv.w*gv.w;
  float ss = hv.x*hv.x + hv.y*hv.y + hv.z*hv.z + hv.w*hv.w;
  float mg = fmaxf(fmaxf(fabsf(pv.x), fabsf(pv.y)), fmaxf(fabsf(pv.z), fabsf(pv.w)));
  #pragma unroll
  for (int o2 = 32; o2 > 0; o2 >>= 1) {
    ss += __shfl_down(ss, o2);
    mg = fmaxf(mg, __shfl_down(mg, o2));
  }
  __shared__ float reds[4], redm[4]; __shared__ float sbc;
  if ((threadIdx.x & 63) == 0) { reds[threadIdx.x >> 6] = ss; redm[threadIdx.x >> 6] = mg; }
  __syncthreads();
  if (threadIdx.x == 0) {
    const float mean = (reds[0]+reds[1]+reds[2]+reds[3]) * (1.f/(float)D);
    const float rn = rsqrtf(mean + 1e-6f);
    const float vmax = rn * fmaxf(fmaxf(redm[0], redm[1]), fmaxf(redm[2], redm[3]));
    const float s = fmaxf(vmax, 1e-8f) * (1.f/127.f);
    sx[row] = s;
    sbc = rn / s;
  }
  __syncthreads();
  const float f = sbc;
  char4 o;
  o.x = (char)__float2int_rn(pv.x * f); o.y = (char)__float2int_rn(pv.y * f);
  o.z = (char)__float2int_rn(pv.z * f); o.w = (char)__float2int_rn(pv.w * f);
  reinterpret_cast<char4*>(q + (size_t)row*D)[threadIdx.x] = o;
}

// ---------------------------------------------------------------------------
// Per-row (len FFD=4096) i8 quantize of the FFN intermediate (f16 in).
// ---------------------------------------------------------------------------
__global__ __launch_bounds__(256) void quant_ffn_kernel(
    const f16* __restrict__ a, char* __restrict__ q, float* __restrict__ s)
{
  const int row = blockIdx.x;
  const size_t base = (size_t)row*(FFD/4);
  f16x4 v[4];
  float mx = 0.f;
  #pragma unroll
  for (int i = 0; i < 4; ++i) {
    v[i] = reinterpret_cast<const f16x4*>(a)[base + threadIdx.x + i*256];
    #pragma unroll
    for (int j = 0; j < 4; ++j) mx = fmaxf(mx, fabsf((float)v[i][j]));
  }
  #pragma unroll
  for (int off = 32; off > 0; off >>= 1) mx = fmaxf(mx, __shfl_down(mx, off));
  __shared__ float red[4]; __shared__ float sbc;
  if ((threadIdx.x & 63) == 0) red[threadIdx.x >> 6] = mx;
  __syncthreads();
  if (threadIdx.x == 0) {
    const float m = fmaxf(fmaxf(red[0], red[1]), fmaxf(red[2], red[3]));
    const float sr = fmaxf(m, 1e-8f) * (1.f/127.f);
    s[row] = sr;
    sbc = 1.f / sr;
  }
  __syncthreads();
  const float inv = sbc;
  #pragma unroll
  for (int i = 0; i < 4; ++i) {
    char4 o;
    o.x = (char)__float2int_rn((float)v[i][0] * inv);
    o.y = (char)__float2int_rn((float)v[i][1] * inv);
    o.z = (char)__float2int_rn((float)v[i][2] * inv);
    o.w = (char)__float2int_rn((float)v[i][3] * inv);
    reinterpret_cast<char4*>(q)[base + threadIdx.x + i*256] = o;
  }
}

// ---------------------------------------------------------------------------
// Time-mix recurrence: chunked prefix sum over T. FAST PATH: r/k/v in f16
// (sigmoid(r) in [0,1]; k,v carry i8-GEMM noise >> f16 rounding).
// ---------------------------------------------------------------------------
__global__ __launch_bounds__(256) void scan1h_kernel(
    const f16* __restrict__ k, const f16* __restrict__ v, int ld,
    const float* __restrict__ decay, float* __restrict__ part)
{
  const int d = blockIdx.x*256 + threadIdx.x;
  const int c = blockIdx.y, b = blockIdx.z;
  const float dec = 1.f / (1.f + expf(-decay[d]));
  const float ldc = logf(fmaxf(dec, 1e-7f));
  float sum = 0.f;
  const int row0 = b*T + c*CT;
  #pragma unroll 4
  for (int t = 0; t < CT; ++t) {
    const size_t i = (size_t)(row0 + t)*ld + d;
    const float scale = expf((float)(c*CT + t) * ldc);
    sum += ((float)k[i] * (float)v[i]) / fmaxf(scale, 1e-10f);
  }
  part[((size_t)b*NT + c)*D + d] = sum;
}

__global__ __launch_bounds__(256) void scan23h_kernel(
    const f16* __restrict__ r, const f16* __restrict__ k,
    const f16* __restrict__ v, int ld, const float* __restrict__ decay,
    const float* __restrict__ part, float* __restrict__ rs)
{
  const int d = blockIdx.x*256 + threadIdx.x;
  const int c = blockIdx.y, b = blockIdx.z;
  const float dec = 1.f / (1.f + expf(-decay[d]));
  const float ldc = logf(fmaxf(dec, 1e-7f));
  float cum = 0.f;
  for (int j = 0; j < c; ++j) cum += part[((size_t)b*NT + j)*D + d];
  const int row0 = b*T + c*CT;
  #pragma unroll 4
  for (int t = 0; t < CT; ++t) {
    const size_t i = (size_t)(row0 + t)*ld + d;
    const float scale = expf((float)(c*CT + t) * ldc);
    cum += ((float)k[i] * (float)v[i]) / fmaxf(scale, 1e-10f);
    rs[(size_t)(row0 + t)*D + d] = (float)r[i] * (cum * scale);
  }
}

// fallback-path kernels (f32 scan) -------------------------------------------
__global__ __launch_bounds__(256) void scan1_kernel(
    const float* __restrict__ k, const float* __restrict__ v, int ld,
    const float* __restrict__ decay, float* __restrict__ part)
{
  const int d = blockIdx.x*256 + threadIdx.x;
  const int c = blockIdx.y, b = blockIdx.z;
  const float dec = 1.f / (1.f + expf(-decay[d]));
  const float ldc = logf(fmaxf(dec, 1e-7f));
  float sum = 0.f;
  const int row0 = b*T + c*CT;
  #pragma unroll 4
  for (int t = 0; t < CT; ++t) {
    const size_t i = (size_t)(row0 + t)*ld + d;
    const float scale = expf((float)(c*CT + t) * ldc);
    sum += (k[i] * v[i]) / fmaxf(scale, 1e-10f);
  }
  part[((size_t)b*NT + c)*D + d] = sum;
}

__global__ __launch_bounds__(256) void rms_f16_kernel(
    const float* __restrict__ x, const float* __restrict__ g, f16* __restrict__ o)
{
  const int row = blockIdx.x;
  const float4 xv = reinterpret_cast<const float4*>(x + (size_t)row*D)[threadIdx.x];
  float ss = xv.x*xv.x + xv.y*xv.y + xv.z*xv.z + xv.w*xv.w;
  #pragma unroll
  for (int off = 32; off > 0; off >>= 1) ss += __shfl_down(ss, off);
  __shared__ float red[4];
  if ((threadIdx.x & 63) == 0) red[threadIdx.x >> 6] = ss;
  __syncthreads();
  const float mean = (red[0]+red[1]+red[2]+red[3]) * (1.f/(float)D);
  const float rn = rsqrtf(mean + 1e-6f);
  const float4 gv = reinterpret_cast<const float4*>(g)[threadIdx.x];
  f16x4 ov;
  ov[0] = (f16)(xv.x*rn*gv.x); ov[1] = (f16)(xv.y*rn*gv.y);
  ov[2] = (f16)(xv.z*rn*gv.z); ov[3] = (f16)(xv.w*rn*gv.w);
  reinterpret_cast<f16x4*>(o + (size_t)row*D)[threadIdx.x] = ov;
}

__global__ __launch_bounds__(256) void scan2_kernel(float* __restrict__ part)
{
  const int d = blockIdx.x*256 + threadIdx.x;
  const int b = blockIdx.y;
  float run = 0.f;
  #pragma unroll 8
  for (int c = 0; c < NT; ++c) {
    const size_t i = ((size_t)b*NT + c)*D + d;
    const float t = part[i];
    part[i] = run;
    run += t;
  }
}

__global__ __launch_bounds__(256) void scan3_kernel(
    const float* __restrict__ r, const float* __restrict__ k,
    const float* __restrict__ v, int ld, const float* __restrict__ decay,
    const float* __restrict__ part, float* __restrict__ rs)
{
  const int d = blockIdx.x*256 + threadIdx.x;
  const int c = blockIdx.y, b = blockIdx.z;
  const float dec = 1.f / (1.f + expf(-decay[d]));
  const float ldc = logf(fmaxf(dec, 1e-7f));
  float cum = part[((size_t)b*NT + c)*D + d];
  const int row0 = b*T + c*CT;
  #pragma unroll 4
  for (int t = 0; t < CT; ++t) {
    const size_t i = (size_t)(row0 + t)*ld + d;
    const float scale = expf((float)(c*CT + t) * ldc);
    cum += (k[i] * v[i]) / fmaxf(scale, 1e-10f);
    rs[(size_t)(row0 + t)*D + d] = r[i] * (cum * scale);
  }
}

__global__ __launch_bounds__(256) void silumul_kernel(
    const f16* __restrict__ a, const f16* __restrict__ b, f16* __restrict__ o, int n4)
{
  const int i = blockIdx.x*256 + threadIdx.x;
  if (i >= n4) return;
  const f16x4 av = reinterpret_cast<const f16x4*>(a)[i];
  const f16x4 bv = reinterpret_cast<const f16x4*>(b)[i];
  f16x4 ov;
  #pragma unroll
  for (int j = 0; j < 4; ++j) {
    const float x = (float)av[j];
    ov[j] = (f16)((x / (1.f + expf(-x))) * (float)bv[j]);
  }
  reinterpret_cast<f16x4*>(o)[i] = ov;
}

// ---------------------------------------------------------------------------
// XCD-chunked bijective block swizzle (m204).
// ---------------------------------------------------------------------------
__device__ __forceinline__ int xcd_swizzle(int fid, int nwg) {
  const int q = nwg >> 3, r = nwg & 7, x = fid & 7, o = fid >> 3;
  return (x < r ? x*(q+1) : r*(q+1) + (x-r)*q) + o;
}

// ---------------------------------------------------------------------------
// RING GEMM, INT8 (r11/r14-proven): 3-buffer, depth-2 prefetch, counted vmcnt,
// ONE barrier/K-step. K-step 64, mfma_i32_16x16x64_i8.
// out[M,N] = epi( sx[row] * scl[col] * (A8 @ W8^T) ). BN=128.
// EPI: 0 none, 2 +resid, 3 sigmoid iff col<D. OUTF16 selects f16 output.
// SPLITK: gridDim.z pieces write outp + z*M*N.
// <128,8,0> doubles as the HEAD (scl=sw, N=V; 48KB LDS -> 3 blocks/CU).
// ---------------------------------------------------------------------------
template<int BM, int NW, int EPI, bool SPLITK = false, bool OUTF16 = false>
__global__ __launch_bounds__(NW*64) void gemm_i8_kernel(
    const char* __restrict__ A, const char* __restrict__ Bq,
    const float* __restrict__ sx, const float* __restrict__ scl,
    const float* __restrict__ resid, void* __restrict__ outp, int N, int K)
{
  constexpr int WN = 2;
  constexpr int WM = NW / WN;
  constexpr int MF = BM / (WM*16);
  constexpr int ACALLS = BM / (16*NW);
  constexpr int BCALLS = 128 / (16*NW);
  constexpr int VCNT = ACALLS + BCALLS;
  __shared__ __align__(16) char As[3][BM*64];
  __shared__ __align__(16) char Bs[3][128*64];

  const int tid = threadIdx.x;
  const int wave = tid >> 6, lane = tid & 63;
  const int gx = gridDim.x, nwg = gx * gridDim.y;
  const int wg = xcd_swizzle(blockIdx.x + blockIdx.y*gx, nwg);
  const int m0 = (wg % gx) * BM, n0 = (wg / gx) * 128;
  const int lr = lane & 15, kg = lane >> 4;
  const int wm0 = (wave / WN) * (MF*16), wn0 = (wave % WN) * 64;
  const int grow = lane >> 2;
  const int gcol = (lane & 3) * 16;
  const char* Ab = A  + (size_t)(m0 + grow)*K + gcol;
  const char* Bb = Bq + (size_t)(n0 + grow)*K + gcol;

  int kbeg = 0, kend = K;
  size_t obase = 0;
  if (SPLITK) {
    const int kc = K / gridDim.z;
    kbeg = blockIdx.z * kc; kend = kbeg + kc;
    obase = (size_t)blockIdx.z * M * (size_t)N;
  }
  const int NKT = (kend - kbeg) / 64;

  auto stage = [&](int buf, int k0) {
    #pragma unroll
    for (int c = 0; c < ACALLS; ++c) {
      const int rb = (c*NW + wave) * 16;
      gload16b(Ab + (size_t)rb*K + k0, &As[buf][rb*64]);
    }
    #pragma unroll
    for (int c = 0; c < BCALLS; ++c) {
      const int rb = (c*NW + wave) * 16;
      gload16b(Bb + (size_t)rb*K + k0, &Bs[buf][rb*64]);
    }
  };

  i32x4 acc[MF][4] = {};
  stage(0, kbeg);
  stage(1, kbeg + 64);

  int cur = 0;
  for (int t = 0; t < NKT; ++t) {
    vm_wait<VCNT>();
    ring_barrier();
    if (t + 2 < NKT) {
      int nb = cur + 2; if (nb >= 3) nb -= 3;
      stage(nb, kbeg + (t + 2) * 64);
    }
    i32x4 af[MF], bf[4];
    #pragma unroll
    for (int i = 0; i < MF; ++i)
      af[i] = *reinterpret_cast<const i32x4*>(&As[cur][(wm0 + i*16 + lr)*64 + kg*16]);
    #pragma unroll
    for (int j = 0; j < 4; ++j)
      bf[j] = *reinterpret_cast<const i32x4*>(&Bs[cur][(wn0 + j*16 + lr)*64 + kg*16]);
    #pragma unroll
    for (int i = 0; i < MF; ++i)
      #pragma unroll
      for (int j = 0; j < 4; ++j)
        acc[i][j] = __builtin_amdgcn_mfma_i32_16x16x64_i8(af[i], bf[j], acc[i][j], 0, 0, 0);
    ++cur; if (cur == 3) cur = 0;
  }

  // C/D frag layout: col=lane&15, row=(lane>>4)*4+e (dtype-independent)
  #pragma unroll
  for (int j = 0; j < 4; ++j) {
    const int col = n0 + wn0 + j*16 + lr;
    const float sv = scl[col];
    #pragma unroll
    for (int i = 0; i < MF; ++i) {
      #pragma unroll
      for (int e = 0; e < 4; ++e) {
        const int row = m0 + wm0 + i*16 + kg*4 + e;
        float y = (float)acc[i][j][e] * sx[row] * sv;
        if (EPI == 3 && col < D) y = 1.f / (1.f + expf(-y));
        if (EPI == 2) y += resid[(size_t)row*N + col];
        if (OUTF16) reinterpret_cast<f16*>(outp)[obase + (size_t)row*N + col] = (f16)y;
        else        reinterpret_cast<float*>(outp)[obase + (size_t)row*N + col] = y;
      }
    }
  }
}

// ---------------------------------------------------------------------------
// RING FUSED FFN GEMM, INT8 (r11-proven): g16 = (f16)( silu(.)*(.) ).
// 128x128 tile, 8 waves, ring-3, K-step 64.
// ---------------------------------------------------------------------------
__global__ __launch_bounds__(512) void gemm_ffn_i8_kernel(
    const char* __restrict__ A, const char* __restrict__ B1, const char* __restrict__ B2,
    const float* __restrict__ sx, const float* __restrict__ s1, const float* __restrict__ s2,
    f16* __restrict__ outg, int N, int K)
{
  constexpr int BM = 128, BN = 128;
  __shared__ __align__(16) char As [3][BM*64];
  __shared__ __align__(16) char B1s[3][BN*64];
  __shared__ __align__(16) char B2s[3][BN*64];
  const int tid = threadIdx.x;
  const int wave = tid >> 6, lane = tid & 63;
  const int gx = gridDim.x, nwg = gx * gridDim.y;
  const int wg = xcd_swizzle(blockIdx.x + blockIdx.y*gx, nwg);
  const int m0 = (wg % gx) * BM, n0 = (wg / gx) * BN;
  const int lr = lane & 15, kg = lane >> 4;
  const int wm0 = (wave >> 1) * 32, wn0 = (wave & 1) * 64;  // 8 waves: 4M x 2N
  const int grow = lane >> 2;
  const int gcol = (lane & 3) * 16;
  const char* Ab  = A  + (size_t)(m0 + grow)*K + gcol;
  const char* B1b = B1 + (size_t)(n0 + grow)*K + gcol;
  const char* B2b = B2 + (size_t)(n0 + grow)*K + gcol;

  auto stage = [&](int buf, int k0) {
    const int rb = wave * 16;
    gload16b(Ab  + (size_t)rb*K + k0, &As [buf][rb*64]);
    gload16b(B1b + (size_t)rb*K + k0, &B1s[buf][rb*64]);
    gload16b(B2b + (size_t)rb*K + k0, &B2s[buf][rb*64]);
  };

  i32x4 aca[2][4] = {};
  i32x4 acb[2][4] = {};
  stage(0, 0);
  stage(1, 64);

  const int NKT = K / 64;
  int cur = 0;
  for (int t = 0; t < NKT; ++t) {
    vm_wait<3>();
    ring_barrier();
    if (t + 2 < NKT) {
      int nb = cur + 2; if (nb >= 3) nb -= 3;
      stage(nb, (t + 2) * 64);
    }
    i32x4 af[2], b1f[4], b2f[4];
    #pragma unroll
    for (int i = 0; i < 2; ++i)
      af[i] = *reinterpret_cast<const i32x4*>(&As[cur][(wm0 + i*16 + lr)*64 + kg*16]);
    #pragma unroll
    for (int j = 0; j < 4; ++j) {
      b1f[j] = *reinterpret_cast<const i32x4*>(&B1s[cur][(wn0 + j*16 + lr)*64 + kg*16]);
      b2f[j] = *reinterpret_cast<const i32x4*>(&B2s[cur][(wn0 + j*16 + lr)*64 + kg*16]);
    }
    #pragma unroll
    for (int i = 0; i < 2; ++i)
      #pragma unroll
      for (int j = 0; j < 4; ++j) {
        aca[i][j] = __builtin_amdgcn_mfma_i32_16x16x64_i8(af[i], b1f[j], aca[i][j], 0, 0, 0);
        acb[i][j] = __builtin_amdgcn_mfma_i32_16x16x64_i8(af[i], b2f[j], acb[i][j], 0, 0, 0);
      }
    ++cur; if (cur == 3) cur = 0;
  }
  #pragma unroll
  for (int j = 0; j < 4; ++j) {
    const int col = n0 + wn0 + j*16 + lr;
    const float sa = s1[col], sb = s2[col];
    #pragma unroll
    for (int i = 0; i < 2; ++i) {
      #pragma unroll
      for (int e = 0; e < 4; ++e) {
        const int row = m0 + wm0 + i*16 + kg*4 + e;
        const float srow = sx[row];
        const float a = (float)aca[i][j][e] * srow * sa;
        const float b = (float)acb[i][j][e] * srow * sb;
        outg[(size_t)row*N + col] = (f16)((a / (1.f + expf(-a))) * b);
      }
    }
  }
}

// ---------------------------------------------------------------------------
// FALLBACK GEMM: inline quantize from f32 weights (used if ws too small).
// ---------------------------------------------------------------------------
__global__ __launch_bounds__(64) void scales_kernel(
    const float* __restrict__ Wr, const float* __restrict__ Wk,
    const float* __restrict__ Wv, const float* __restrict__ Wo,
    const float* __restrict__ W1, const float* __restrict__ W2,
    const float* __restrict__ Woc, float* __restrict__ s)
{
  const int r = blockIdx.x, l = blockIdx.y;
  const float* base; int len;
  if (r < 4*D) {
    const int m = r >> 10, row = r & (D-1);
    const float* Wm = (m==0) ? Wr : (m==1) ? Wk : (m==2) ? Wv : Wo;
    base = Wm + (size_t)l*D*D + (size_t)row*D; len = D;
  } else if (r < 4*D + 2*FFD) {
    int row = r - 4*D;
    const float* Wm = (row < FFD) ? W1 : W2;
    if (row >= FFD) row -= FFD;
    base = Wm + (size_t)l*FFD*D + (size_t)row*D; len = D;
  } else {
    const int row = r - (4*D + 2*FFD);
    base = Woc + (size_t)l*D*FFD + (size_t)row*FFD; len = FFD;
  }
  float sum = 0.f;
  for (int i = threadIdx.x; i < len; i += 64) sum += fabsf(base[i]);
  #pragma unroll
  for (int off = 32; off > 0; off >>= 1) sum += __shfl_down(sum, off);
  if (threadIdx.x == 0)
    s[(size_t)l*ROWS_PER_LAYER + r] = fmaxf(sum / (float)len, 1e-5f);
}

template<int BM, int EPI, bool QUANT, bool OUTF16>
__global__ __launch_bounds__(256) void gemm_bt_kernel(
    const f16* __restrict__ A, const float* __restrict__ Bw,
    const float* __restrict__ scl, const float* __restrict__ resid,
    void* __restrict__ outp, int N, int K)
{
  constexpr int BN = 128, LDT = 40;
  constexpr int MF = (BM == 128) ? 4 : 2;
  __shared__ f16 As[BM*LDT];
  __shared__ f16 Bs[BN*LDT];
  const int tid = threadIdx.x;
  const int m0 = blockIdx.y * BM, n0 = blockIdx.x * BN;
  const int wave = tid >> 6, lane = tid & 63;
  const int lr = lane & 15, kg = lane >> 4;
  const int wm0 = (wave >> 1) * (MF*16), wn0 = (wave & 1) * 64;
  f32x4 acc[MF][4] = {};
  for (int k0 = 0; k0 < K; k0 += 32) {
    #pragma unroll
    for (int c = 0; c < (BM*4)/256; ++c) {
      const int chunk = tid + c*256;
      const int row = chunk >> 2, c8 = (chunk & 3) << 3;
      *reinterpret_cast<f16x8*>(&As[row*LDT + c8]) =
        *reinterpret_cast<const f16x8*>(A + (size_t)(m0+row)*K + k0 + c8);
    }
    #pragma unroll
    for (int c = 0; c < 2; ++c) {
      const int chunk = tid + c*256;
      const int row = chunk >> 2, c8 = (chunk & 3) << 3;
      const float* bp = Bw + (size_t)(n0+row)*K + k0 + c8;
      const float4 f0 = *reinterpret_cast<const float4*>(bp);
      const float4 f1 = *reinterpret_cast<const float4*>(bp + 4);
      const float wv[8] = {f0.x,f0.y,f0.z,f0.w,f1.x,f1.y,f1.z,f1.w};
      f16x8 qv;
      if (QUANT) {
        const float hs = 0.5f * scl[n0+row];
        #pragma unroll
        for (int j = 0; j < 8; ++j)
          qv[j] = wv[j] > hs ? (f16)1.f : (wv[j] < -hs ? (f16)(-1.f) : (f16)0.f);
      } else {
        #pragma unroll
        for (int j = 0; j < 8; ++j) qv[j] = (f16)wv[j];
      }
      *reinterpret_cast<f16x8*>(&Bs[row*LDT + c8]) = qv;
    }
    __syncthreads();
    f16x8 af[MF], bf[4];
    #pragma unroll
    for (int i = 0; i < MF; ++i)
      af[i] = *reinterpret_cast<const f16x8*>(&As[(wm0 + i*16 + lr)*LDT + kg*8]);
    #pragma unroll
    for (int j = 0; j < 4; ++j)
      bf[j] = *reinterpret_cast<const f16x8*>(&Bs[(wn0 + j*16 + lr)*LDT + kg*8]);
    #pragma unroll
    for (int i = 0; i < MF; ++i)
      #pragma unroll
      for (int j = 0; j < 4; ++j)
        acc[i][j] = __builtin_amdgcn_mfma_f32_16x16x32_f16(af[i], bf[j], acc[i][j], 0, 0, 0);
    __syncthreads();
  }
  #pragma unroll
  for (int j = 0; j < 4; ++j) {
    const int col = n0 + wn0 + j*16 + lr;
    const float sv = QUANT ? scl[col] : 1.f;
    #pragma unroll
    for (int i = 0; i < MF; ++i) {
      #pragma unroll
      for (int e = 0; e < 4; ++e) {
        const int row = m0 + wm0 + i*16 + kg*4 + e;
        float y = acc[i][j][e] * sv;
        if (EPI == 1) y = 1.f / (1.f + expf(-y));
        if (EPI == 2) y += resid[(size_t)row*N + col];
        if (OUTF16) reinterpret_cast<f16*>(outp)[(size_t)row*N + col] = (f16)y;
        else        reinterpret_cast<float*>(outp)[(size_t)row*N + col] = y;
      }
    }
  }
}

// ---------------------------------------------------------------------------
extern "C" void kernel_launch(void* const* d_in, const int* in_sizes, int n_in,
                              void* d_out, int out_size, void* d_ws, size_t ws_size,
                              hipStream_t stream)
{
  (void)in_sizes; (void)n_in; (void)out_size;
  const int*   idx      = (const int*)  d_in[0];
  const float* embed    = (const float*)d_in[1];
  const float* ln_in_w  = (const float*)d_in[2];
  const float* ln1_w    = (const float*)d_in[3];
  const float* Wr       = (const float*)d_in[4];
  const float* Wk       = (const float*)d_in[5];
  const float* Wv       = (const float*)d_in[6];
  const float* Wo_t     = (const float*)d_in[7];
  const float* decay    = (const float*)d_in[8];
  const float* lnx_w    = (const float*)d_in[9];
  const float* ln2_w    = (const float*)d_in[10];
  const float* W1       = (const float*)d_in[11];
  const float* W2       = (const float*)d_in[12];
  const float* Wo_c     = (const float*)d_in[13];
  const float* ln_out_w = (const float*)d_in[14];
  float* out = (float*)d_out;

  char* p = (char*)d_ws;
  auto alloc = [&](size_t bytes) { void* q = (void*)p; p += (bytes + 255) & ~(size_t)255; return q; };
  float* h      = (float*)alloc((size_t)M*D*sizeof(float));
  f16*   xn     = (f16*)  alloc((size_t)M*D*sizeof(f16));       // fallback only
  float* rkv    = (float*)alloc((size_t)M*RKV*sizeof(float));   // fallback r|k|v; fast: split-K partials
  float* rsb    = (float*)alloc((size_t)M*D*sizeof(float));
  f16*   abf    = (f16*)  alloc((size_t)M*FFD*sizeof(f16));
  f16*   bbf    = (f16*)  alloc((size_t)M*FFD*sizeof(f16));     // fallback only
  float* scales = (float*)alloc((size_t)NL*ROWS_PER_LAYER*sizeof(float));
  float* part   = (float*)alloc((size_t)BB*NT*D*sizeof(float));
  const size_t base_need = (size_t)(p - (char*)d_ws);
  const size_t fast_need = base_need + (NL*QL + 256)
      + ((size_t)V*D + 256) + (V*sizeof(float) + 256)
      + ((size_t)M*D + 256) + (M*sizeof(float) + 256)
      + ((size_t)M*FFD + 256) + (M*sizeof(float) + 256)
      + ((size_t)M*RKV*sizeof(f16) + 256);

  embed_rms_kernel<<<M, 256, 0, stream>>>(idx, embed, ln_in_w, h);

  const dim3 gS(D/256, NT, BB);   // scan1/scan23: 512 blocks
  const dim3 gS2(D/256, BB);      // scan2 (fallback): 8 blocks

  if (ws_size >= fast_need) {
    // ================= FAST PATH: i8 weights + i8 activations =================
    char*  qw8   = (char*) alloc(NL*QL);
    char*  emb8  = (char*) alloc((size_t)V*D);
    float* sw    = (float*)alloc((size_t)V*sizeof(float));
    char*  xn8   = (char*) alloc((size_t)M*D);
    float* sx    = (float*)alloc((size_t)M*sizeof(float));
    char*  abf8  = (char*) alloc((size_t)M*FFD);
    float* sax   = (float*)alloc((size_t)M*sizeof(float));
    f16*   rkv16 = (f16*)  alloc((size_t)M*RKV*sizeof(f16));    // f16 r|k|v
    quant_kernel<<<dim3(ROWS_PER_LAYER, NL), 256, 0, stream>>>(Wr, Wk, Wv, Wo_t, W1, W2, Wo_c, qw8, scales);
    quant_embed_kernel<<<V, 256, 0, stream>>>(embed, emb8, sw);

    const dim3 gRKV(M/128, RKV/128);     // 16 x 24 = 384 blocks, 8 waves
    const dim3 gO(M/64, D/128);          // 32 x 8  = 256 blocks, 4 waves
    const dim3 gOC(M/64, D/128, 2);      // 512 blocks (split-K x2)
    const dim3 gFFN(M/128, FFD/128);     // 16 x 32 = 512 blocks, 8 waves
    const dim3 gHEAD(M/128, V/128);      // 16 x 250 = 4000 blocks, 8 waves, 48KB LDS

    rms_i8_kernel<<<M, 256, 0, stream>>>(h, ln1_w, xn8, sx);   // first layer's ln1
    for (int l = 0; l < NL; ++l) {
      const float* sl = scales + (size_t)l*ROWS_PER_LAYER;
      const char* qb = qw8 + (size_t)l*QL;
      const char *qrkv = qb, *qo = qb + 3ull*D*D;
      const char *q1 = qb + 4ull*D*D, *q2 = qb + 4ull*D*D + (size_t)FFD*D;
      const char *qoc = qb + 4ull*D*D + 2ull*(size_t)FFD*D;
      const float* dcy = decay + (size_t)l*D;
      // ---- time mix (rkv in f16: halves scan-path traffic) ----
      gemm_i8_kernel<128,8,3,false,true><<<gRKV, 512, 0, stream>>>(xn8, qrkv, sx, sl, nullptr, rkv16, RKV, D);
      scan1h_kernel<<<gS, 256, 0, stream>>>(rkv16 + D, rkv16 + 2*D, RKV, dcy, part);
      scan23h_kernel<<<gS, 256, 0, stream>>>(rkv16, rkv16 + D, rkv16 + 2*D, RKV, dcy, part, rsb);
      rms_i8_kernel<<<M, 256, 0, stream>>>(rsb, lnx_w + (size_t)l*D, xn8, sx);
      gemm_i8_kernel<64,4,2><<<gO, 256, 0, stream>>>(xn8, qo, sx, sl + 3*D, h, h, D, D);
      // ---- channel mix ----
      rms_i8_kernel<<<M, 256, 0, stream>>>(h, ln2_w + (size_t)l*D, xn8, sx);
      gemm_ffn_i8_kernel<<<gFFN, 512, 0, stream>>>(xn8, q1, q2, sx, sl + 4*D, sl + 4*D + FFD, abf, FFD, D);
      quant_ffn_kernel<<<M, 256, 0, stream>>>(abf, abf8, sax);
      gemm_i8_kernel<64,4,0,true><<<gOC, 256, 0, stream>>>(abf8, qoc, sax, sl + 4*D + 2*FFD, nullptr, rkv, D, FFD);
      const float* gnext = (l + 1 < NL) ? (ln1_w + (size_t)(l+1)*D) : ln_out_w;
      rms_radd_i8_kernel<<<M, 256, 0, stream>>>(h, rkv, rkv + (size_t)M*D, gnext, xn8, sx);
    }
    // ---- weight-tied head: proven 128x128 8-wave i8 ring (48KB LDS) ----
    gemm_i8_kernel<128,8,0><<<gHEAD, 512, 0, stream>>>(xn8, emb8, sx, sw, nullptr, out, V, D);
  } else {
    // ================= FALLBACK: inline-quant f16 path =================
    float* rbuf = rkv;
    float* kbuf = rkv + (size_t)M*D;
    float* vbuf = rkv + 2ull*M*D;
    scales_kernel<<<dim3(ROWS_PER_LAYER, NL), 64, 0, stream>>>(Wr, Wk, Wv, Wo_t, W1, W2, Wo_c, scales);
    const dim3 gD(D/128, M/64);
    const dim3 gF(FFD/128, M/128);
    for (int l = 0; l < NL; ++l) {
      const float* sl = scales + (size_t)l*ROWS_PER_LAYER;
      const float* dcy = decay + (size_t)l*D;
      rms_f16_kernel<<<M, 256, 0, stream>>>(h, ln1_w + (size_t)l*D, xn);
      gemm_bt_kernel<64,1,true,false><<<gD, 256, 0, stream>>>(xn, Wr + (size_t)l*D*D, sl,       nullptr, rbuf, D, D);
      gemm_bt_kernel<64,0,true,false><<<gD, 256, 0, stream>>>(xn, Wk + (size_t)l*D*D, sl + D,   nullptr, kbuf, D, D);
      gemm_bt_kernel<64,0,true,false><<<gD, 256, 0, stream>>>(xn, Wv + (size_t)l*D*D, sl + 2*D, nullptr, vbuf, D, D);
      scan1_kernel<<<gS, 256, 0, stream>>>(kbuf, vbuf, D, dcy, part);
      scan2_kernel<<<gS2, 256, 0, stream>>>(part);
      scan3_kernel<<<gS, 256, 0, stream>>>(rbuf, kbuf, vbuf, D, dcy, part, rsb);
      rms_f16_kernel<<<M, 256, 0, stream>>>(rsb, lnx_w + (size_t)l*D, xn);
      gemm_bt_kernel<64,2,true,false><<<gD, 256, 0, stream>>>(xn, Wo_t + (size_t)l*D*D, sl + 3*D, h, h, D, D);
      rms_f16_kernel<<<M, 256, 0, stream>>>(h, ln2_w + (size_t)l*D, xn);
      gemm_bt_kernel<128,0,true,true><<<gF, 256, 0, stream>>>(xn, W1 + (size_t)l*FFD*D, sl + 4*D,       nullptr, abf, FFD, D);
      gemm_bt_kernel<128,0,true,true><<<gF, 256, 0, stream>>>(xn, W2 + (size_t)l*FFD*D, sl + 4*D + FFD, nullptr, bbf, FFD, D);
      silumul_kernel<<<(M*FFD/4)/256, 256, 0, stream>>>(abf, bbf, abf, M*FFD/4);
      gemm_bt_kernel<64,2,true,false><<<gD, 256, 0, stream>>>(abf, Wo_c + (size_t)l*D*FFD, sl + 4*D + 2*FFD, h, h, D, FFD);
    }
    rms_f16_kernel<<<M, 256, 0, stream>>>(h, ln_out_w, xn);
    gemm_bt_kernel<128,0,false,false><<<dim3(V/128, M/128), 256, 0, stream>>>(xn, embed, nullptr, nullptr, out, V, D);
  }
}